// Round 1
// baseline (132669.580 us; speedup 1.0000x reference)
//
#include <hip/hip_runtime.h>
#include <stdint.h>

// Transducer greedy decode, persistent-kernel design.
// B=32 T=1000 D=640 V=1024, gates=4*640=2560.
// Stages (one persistent kernel, 192 blocks x 256 thr):
//   A (40 blk): zpart = W_tn . tn_t  and  W_pn . out_pn   (per 32-j tile, in-block d-split 8)
//   Z ( 8 blk): X_z = tanh(b_joint + zpart0 + zpart1)
//   L (32 blk): logits tile = W_out . X_z (+b_out); per-b atomicMax(packed key), atomicAdd(sumexp)
//   C (80 blk): g_final = W_hh . h
//   F (32 blk): decode argmax -> tok/lp/score/emit; LSTM elementwise with P[tok] gather
// Sync: monotone device-scope counters; relaxed spin + __threadfence (agent acq) / release add.

typedef unsigned long long u64;
typedef uint32_t u32;

#define BB 32
#define TT 1000
#define DD 640
#define GG 2560
#define VV 1024

#define NA 40
#define NZ 8
#define NL 32
#define NC 80
#define NF 32
#define NBLK (NA + NZ + NL + NC + NF) // 192

// ws layout (float offsets)
static constexpr size_t OFF_WTN  = 0;                       // 640*640  WT4 layout
static constexpr size_t OFF_WPN  = OFF_WTN  + 409600;
static constexpr size_t OFF_WHH  = OFF_WPN  + 409600;       // 2560*640
static constexpr size_t OFF_WOUT = OFF_WHH  + 1638400;      // 1024*640
static constexpr size_t OFF_P    = OFF_WOUT + 655360;       // 1024*2560
static constexpr size_t OFF_XH   = OFF_P    + 2621440;      // h      [b][640]
static constexpr size_t OFF_XOP  = OFF_XH   + 20480;        // out_pn [b][640]
static constexpr size_t OFF_XZ   = OFF_XOP  + 20480;        // tanh z [b][640]
static constexpr size_t OFF_CST  = OFF_XZ   + 20480;        // c      [b][640]
static constexpr size_t OFF_ZP   = OFF_CST  + 20480;        // zpart  [2][b][640]
static constexpr size_t OFF_GF   = OFF_ZP   + 40960;        // gates  [b][2560]
static constexpr size_t OFF_SC   = OFF_GF   + 81920;        // score[32]
static constexpr size_t OFF_GS   = OFF_SC   + 32;           // sumexp[32]
static constexpr size_t OFF_KEY  = OFF_GS   + 32;           // u64 key[32] (64 floats)
static constexpr size_t OFF_LT   = OFF_KEY  + 64;           // last_tok[32] int
static constexpr size_t OFF_CNT  = OFF_LT   + 32;           // 5 counters, stride 32 ints
static constexpr size_t OFF_END  = OFF_CNT  + 160;

__device__ __forceinline__ float sigf(float x) { return 1.0f / (1.0f + expf(-x)); }

__device__ __forceinline__ u32 ordf(float f) {
  u32 u = __float_as_uint(f);
  return (u & 0x80000000u) ? ~u : (u | 0x80000000u);
}

__device__ __forceinline__ void wait_ge(int* cnt, int target) {
  if (threadIdx.x == 0) {
    while (__hip_atomic_load(cnt, __ATOMIC_RELAXED, __HIP_MEMORY_SCOPE_AGENT) < target)
      __builtin_amdgcn_s_sleep(2);
    __threadfence(); // agent acquire (L1/L2 inv on gfx95x)
  }
  __syncthreads();
}

__device__ __forceinline__ void stage_done(int* cnt) {
  __syncthreads(); // drains vmcnt for all waves -> block stores in L2
  if (threadIdx.x == 0) {
    __hip_atomic_fetch_add(cnt, 1, __ATOMIC_RELEASE, __HIP_MEMORY_SCOPE_AGENT);
  }
}

// batched matvec core: 32-j tile (lane jj), in-block d-split 8 (dq), 32 batch accs.
template <int J>
__device__ __forceinline__ void mv32(const float4* __restrict__ Wq,
                                     const float* __restrict__ X, size_t bstride,
                                     int dbase, float acc[32]) {
#pragma unroll
  for (int b = 0; b < 32; ++b) acc[b] = 0.f;
  for (int q = 0; q < 20; ++q) {
    float4 w = Wq[(size_t)q * J];
    const float* xp = X + dbase + q * 4;
#pragma unroll
    for (int b = 0; b < 32; ++b) {
      float4 xv = *(const float4*)(xp + (size_t)b * bstride);
      acc[b] = fmaf(xv.x, w.x, acc[b]);
      acc[b] = fmaf(xv.y, w.y, acc[b]);
      acc[b] = fmaf(xv.z, w.z, acc[b]);
      acc[b] = fmaf(xv.w, w.w, acc[b]);
    }
  }
}

// ---- setup kernels ----

// W[j][d] (row-major, K=640) -> WT4: float4 at index (d/4)*J + j holds W[j][4q..4q+3]
__global__ __launch_bounds__(256) void k_wt4(const float* __restrict__ W,
                                             float* __restrict__ WT4, int J) {
  __shared__ float tile[64][65];
  int nj = J >> 6;
  int tj = blockIdx.x % nj, tk = blockIdx.x / nj;
  int jb = tj << 6, kb = tk << 6;
  for (int i = threadIdx.x; i < 4096; i += 256) {
    int d = i & 63, j = i >> 6;
    tile[j][d] = W[(size_t)(jb + j) * DD + (kb + d)];
  }
  __syncthreads();
  for (int i = threadIdx.x; i < 1024; i += 256) {
    int j = i & 63, q = i >> 6; // q 0..15
    float4 v = make_float4(tile[j][q * 4], tile[j][q * 4 + 1], tile[j][q * 4 + 2],
                           tile[j][q * 4 + 3]);
    ((float4*)WT4)[(size_t)((kb >> 2) + q) * J + (jb + j)] = v;
  }
}

// P[v][g] = sum_d E[v][d] * Wih[g][d]
__global__ __launch_bounds__(256) void k_pgemm(const float* __restrict__ E,
                                               const float* __restrict__ Wih,
                                               float* __restrict__ P) {
  __shared__ float As[16][65], Bs[16][65];
  int vt = blockIdx.x & 15, gt = blockIdx.x >> 4;
  int vb = vt << 6, gb = gt << 6;
  int tv = threadIdx.x & 15, tg = threadIdx.x >> 4;
  float acc[4][4] = {};
  for (int kb = 0; kb < DD; kb += 16) {
    for (int i = threadIdx.x; i < 1024; i += 256) {
      int k = i & 15, x = i >> 4;
      As[k][x] = E[(size_t)(vb + x) * DD + kb + k];
      Bs[k][x] = Wih[(size_t)(gb + x) * DD + kb + k];
    }
    __syncthreads();
#pragma unroll
    for (int k = 0; k < 16; ++k) {
      float av[4], bv[4];
#pragma unroll
      for (int i = 0; i < 4; ++i) av[i] = As[k][tv * 4 + i];
#pragma unroll
      for (int j = 0; j < 4; ++j) bv[j] = Bs[k][tg * 4 + j];
#pragma unroll
      for (int i = 0; i < 4; ++i)
#pragma unroll
        for (int j = 0; j < 4; ++j) acc[i][j] = fmaf(av[i], bv[j], acc[i][j]);
    }
    __syncthreads();
  }
#pragma unroll
  for (int i = 0; i < 4; ++i)
#pragma unroll
    for (int j = 0; j < 4; ++j)
      P[(size_t)(vb + tv * 4 + i) * GG + gb + tg * 4 + j] = acc[i][j];
}

// initial LSTM step: x0 = E[0], h0=c0=0 -> gates = P[0] + b_lstm (identical for all b)
__global__ __launch_bounds__(256) void k_init(float* __restrict__ ws,
                                              const float* __restrict__ b_lstm) {
  const float* P = ws + OFF_P;
  float* XH = ws + OFF_XH;
  float* XOP = ws + OFF_XOP;
  float* CS = ws + OFF_CST;
  int tid = blockIdx.x * 256 + threadIdx.x;
  if (tid < DD) {
    int j = tid;
    float gi = P[j] + b_lstm[j];
    float gg = P[1280 + j] + b_lstm[1280 + j];
    float go = P[1920 + j] + b_lstm[1920 + j];
    float c1 = sigf(gi) * tanhf(gg); // sig(f)*c0 = 0
    float h1 = sigf(go) * tanhf(c1);
    for (int b = 0; b < BB; ++b) {
      XH[b * DD + j] = h1;
      XOP[b * DD + j] = h1;
      CS[b * DD + j] = c1;
    }
  }
  if (blockIdx.x == 3) {
    int t = threadIdx.x;
    if (t < 32) {
      (ws + OFF_SC)[t] = 0.f;
      (ws + OFF_GS)[t] = 0.f;
      ((u64*)(ws + OFF_KEY))[t] = 0ull;
      ((int*)(ws + OFF_LT))[t] = 0;
    }
    if (t < 5) ((int*)(ws + OFF_CNT))[t * 32] = 0;
  }
}

// ---- persistent decode ----
__global__ __launch_bounds__(256) void k_decode(float* __restrict__ ws,
                                                const float* __restrict__ tn,
                                                const float* __restrict__ b_lstm,
                                                const float* __restrict__ b_joint,
                                                const float* __restrict__ b_out,
                                                float* __restrict__ out) {
  const float* WTN = ws + OFF_WTN;
  const float* WPN = ws + OFF_WPN;
  const float* WHH = ws + OFF_WHH;
  const float* WOUT = ws + OFF_WOUT;
  const float* P = ws + OFF_P;
  float* XH = ws + OFF_XH;
  float* XOP = ws + OFF_XOP;
  float* XZ = ws + OFF_XZ;
  float* CS = ws + OFF_CST;
  float* ZP = ws + OFF_ZP;
  float* GF = ws + OFF_GF;
  float* SC = ws + OFF_SC;
  float* GS = ws + OFF_GS;
  u64* KEY = (u64*)(ws + OFF_KEY);
  int* LT = (int*)(ws + OFF_LT);
  int* CNT = (int*)(ws + OFF_CNT);
  int* cntA = CNT + 0;
  int* cntZ = CNT + 32;
  int* cntL = CNT + 64;
  int* cntC = CNT + 96;
  int* cntF = CNT + 128;

  __shared__ float red[8][32][33]; // ~34KB
  __shared__ float lgt[32][33];
  __shared__ int sh_tok, sh_nb;

  const int bid = blockIdx.x, tid = threadIdx.x;
  const int jj = tid & 31, dq = tid >> 5; // matvec mapping
  const int dbase = dq * 80;
  const int bq = dq; // combine mapping reuses tid>>5

  if (bid < NA) {
    // ---- stage A: zpart[mat] = W . x ----
    const int mat = bid / 20, jt = bid % 20, jbase = jt * 32;
    const float* W4 = (mat == 0) ? WTN : WPN;
    const float4* Wq = (const float4*)W4 + (size_t)(dbase >> 2) * DD + (jbase + jj);
    for (int t = 0; t < TT; ++t) {
      wait_ge(cntF, 32 * t);
      const float* Xb = (mat == 0) ? (tn + (size_t)t * DD) : XOP;
      const size_t bstride = (mat == 0) ? (size_t)TT * DD : (size_t)DD;
      float acc[32];
      mv32<DD>(Wq, Xb, bstride, dbase, acc);
#pragma unroll
      for (int b = 0; b < 32; ++b) red[dq][b][jj] = acc[b];
      __syncthreads();
#pragma unroll
      for (int k = 0; k < 4; ++k) {
        int b = bq * 4 + k;
        float s = 0.f;
#pragma unroll
        for (int d2 = 0; d2 < 8; ++d2) s += red[d2][b][jj];
        ZP[(size_t)mat * 20480 + (size_t)b * DD + jbase + jj] = s;
      }
      stage_done(cntA);
    }
  } else if (bid < NA + NZ) {
    // ---- stage Z: X_z = tanh(b_joint + zp0 + zp1) ----
    const int zi = bid - NA;
    for (int t = 0; t < TT; ++t) {
      wait_ge(cntA, 40 * (t + 1));
      for (int e = zi * 2560 + tid; e < zi * 2560 + 2560; e += 256) {
        int jz = e - (e / DD) * DD;
        XZ[e] = tanhf(b_joint[jz] + ZP[e] + ZP[20480 + e]);
      }
      stage_done(cntZ);
    }
  } else if (bid < NA + NZ + NL) {
    // ---- stage L: logits + per-b argmax/sumexp atomics ----
    const int vt = bid - (NA + NZ), vbase = vt * 32;
    const float4* Wq = (const float4*)WOUT + (size_t)(dbase >> 2) * VV + (vbase + jj);
    for (int t = 0; t < TT; ++t) {
      wait_ge(cntZ, 8 * (t + 1));
      float acc[32];
      mv32<VV>(Wq, XZ, (size_t)DD, dbase, acc);
#pragma unroll
      for (int b = 0; b < 32; ++b) red[dq][b][jj] = acc[b];
      __syncthreads();
      float bo = b_out[vbase + jj];
#pragma unroll
      for (int k = 0; k < 4; ++k) {
        int b = bq * 4 + k;
        float s = bo;
#pragma unroll
        for (int d2 = 0; d2 < 8; ++d2) s += red[d2][b][jj];
        lgt[jj][b] = s;
      }
      __syncthreads();
      if (tid < 32) {
        int b = tid;
        float m = -1e30f;
        int vbest = 0;
        float se = 0.f;
        for (int v = 0; v < 32; ++v) {
          float x = lgt[v][b];
          se += expf(x);
          if (x > m) { m = x; vbest = v; } // strict > => first occurrence in tile
        }
        u64 key = ((u64)ordf(m) << 32) | (u64)(0xFFFFFFFFu - (u32)(vbase + vbest));
        atomicMax(&KEY[b], key);
        atomicAdd(&GS[b], se);
      }
      stage_done(cntL);
    }
  } else if (bid < NA + NZ + NL + NC) {
    // ---- stage C: g_final = W_hh . h ----
    const int jt = bid - (NA + NZ + NL), jbase = jt * 32;
    const float4* Wq = (const float4*)WHH + (size_t)(dbase >> 2) * GG + (jbase + jj);
    for (int t = 0; t < TT; ++t) {
      wait_ge(cntF, 32 * t);
      float acc[32];
      mv32<GG>(Wq, XH, (size_t)DD, dbase, acc);
#pragma unroll
      for (int b = 0; b < 32; ++b) red[dq][b][jj] = acc[b];
      __syncthreads();
#pragma unroll
      for (int k = 0; k < 4; ++k) {
        int b = bq * 4 + k;
        float s = 0.f;
#pragma unroll
        for (int d2 = 0; d2 < 8; ++d2) s += red[d2][b][jj];
        GF[(size_t)b * GG + jbase + jj] = s;
      }
      stage_done(cntC);
    }
  } else {
    // ---- stage F: decode + LSTM elementwise ----
    const int b = bid - (NA + NZ + NL + NC);
    for (int t = 0; t < TT; ++t) {
      wait_ge(cntL, 32 * (t + 1));
      wait_ge(cntC, 80 * (t + 1));
      if (tid == 0) {
        u64 key = __hip_atomic_load(&KEY[b], __ATOMIC_RELAXED, __HIP_MEMORY_SCOPE_AGENT);
        u32 ou = (u32)(key >> 32);
        u32 fb = (ou & 0x80000000u) ? (ou & 0x7FFFFFFFu) : ~ou;
        float m = __uint_as_float(fb);
        int v = (int)(0xFFFFFFFFu - (u32)(key & 0xFFFFFFFFull));
        float S = __hip_atomic_load(&GS[b], __ATOMIC_RELAXED, __HIP_MEMORY_SCOPE_AGENT);
        float lp = m - logf(S); // logits bounded (|l|<~21): no max-shift needed
        int nb = (v != 0) ? 1 : 0;
        if (nb) SC[b] += lp;
        int tok = nb ? v : LT[b];
        LT[b] = tok;
        out[(size_t)b * TT + t] = nb ? (float)v : 0.0f;
        sh_tok = tok;
        sh_nb = nb;
        __hip_atomic_store(&KEY[b], 0ull, __ATOMIC_RELAXED, __HIP_MEMORY_SCOPE_AGENT);
        __hip_atomic_store(&GS[b], 0.f, __ATOMIC_RELAXED, __HIP_MEMORY_SCOPE_AGENT);
      }
      __syncthreads();
      int tok = sh_tok, nb = sh_nb;
      if (nb) {
        const float* Pr = P + (size_t)tok * GG;
        for (int j = tid; j < DD; j += 256) {
          size_t gb = (size_t)b * GG + j;
          float gi = GF[gb] + Pr[j] + b_lstm[j];
          float gf = GF[gb + 640] + Pr[640 + j] + b_lstm[640 + j];
          float gg = GF[gb + 1280] + Pr[1280 + j] + b_lstm[1280 + j];
          float go = GF[gb + 1920] + Pr[1920 + j] + b_lstm[1920 + j];
          float c = CS[b * DD + j];
          float cn = sigf(gf) * c + sigf(gi) * tanhf(gg);
          float hn = sigf(go) * tanhf(cn);
          CS[b * DD + j] = cn;
          XH[b * DD + j] = hn;
          XOP[b * DD + j] = hn;
        }
      }
      stage_done(cntF);
    }
  }
}

__global__ __launch_bounds__(64) void k_final(const float* __restrict__ ws,
                                              float* __restrict__ out) {
  __shared__ float sh[32];
  int t = threadIdx.x;
  if (t < 32) {
    float s = ws[OFF_SC + t];
    out[32000 + t] = s;
    sh[t] = expf(s);
  }
  __syncthreads();
  if (t == 0) {
    float a = 0.f;
    for (int i = 0; i < 32; ++i) a += sh[i];
    out[32032] = a / 32.0f;
  }
}

extern "C" void kernel_launch(void* const* d_in, const int* in_sizes, int n_in,
                              void* d_out, int out_size, void* d_ws, size_t ws_size,
                              hipStream_t stream) {
  const float* tn = (const float*)d_in[0];
  const float* E = (const float*)d_in[1];
  const float* Wih = (const float*)d_in[2];
  const float* Whh = (const float*)d_in[3];
  const float* bl = (const float*)d_in[4];
  const float* Wtn = (const float*)d_in[5];
  const float* Wpn = (const float*)d_in[6];
  const float* bj = (const float*)d_in[7];
  const float* Wout = (const float*)d_in[8];
  const float* bo = (const float*)d_in[9];
  float* ws = (float*)d_ws;
  float* out = (float*)d_out;
  // needs ~22.7 MiB of ws (OFF_END*4 bytes)

  k_wt4<<<100, 256, 0, stream>>>(Wtn, ws + OFF_WTN, DD);
  k_wt4<<<100, 256, 0, stream>>>(Wpn, ws + OFF_WPN, DD);
  k_wt4<<<400, 256, 0, stream>>>(Whh, ws + OFF_WHH, GG);
  k_wt4<<<160, 256, 0, stream>>>(Wout, ws + OFF_WOUT, VV);
  k_pgemm<<<640, 256, 0, stream>>>(E, Wih, ws + OFF_P);
  k_init<<<4, 256, 0, stream>>>(ws, bl);
  k_decode<<<NBLK, 256, 0, stream>>>(ws, tn, bl, bj, bo, out);
  k_final<<<1, 64, 0, stream>>>(ws, out);
}

// Round 2
// 72814.771 us; speedup vs baseline: 1.8220x; 1.8220x over previous
//
#include <hip/hip_runtime.h>
#include <stdint.h>

// Transducer greedy decode, persistent 3-stage pipeline.
// B=32 T=1000 D=640 V=1024, gates=4*640=2560.  out_pn == h (identical updates).
// Stages (one persistent kernel, 304 blocks x 256 thr, 2 blocks/CU co-resident):
//   A (80 blk, 8 j each): z = tanh(W_tn.tn_t + W_pn.h + b_joint) -> XZ
//   L (64 blk, 16 v each): logits = W_out.XZ + b_out; per-b atomicMax key + atomicAdd sumexp
//   C (160 blk, 4 j x 4 gates): gates = W_hh.h ; then decode argmax + LSTM elementwise
//      (c-state in block LDS; h double-buffered by parity; P[tok] row gather)
// Chain per step: C(t-1) -> A(t) -> L(t) -> C-elem(t).  3 handoffs.
// Sync: monotone device counters; relaxed spin + __threadfence / release add (R1-validated).

typedef unsigned long long u64;
typedef uint32_t u32;

#define TT 1000
#define DD 640
#define GG 2560
#define VV 1024

#define NA 80
#define NL 64
#define NC 160
#define NBLK (NA + NL + NC) // 304

// ws layout (float offsets)
static constexpr size_t OFF_WTN  = 0;                      // 640x640  WT4 layout
static constexpr size_t OFF_WPN  = OFF_WTN  + 409600;
static constexpr size_t OFF_WHH  = OFF_WPN  + 409600;      // 2560x640
static constexpr size_t OFF_WOUT = OFF_WHH  + 1638400;     // 1024x640
static constexpr size_t OFF_P    = OFF_WOUT + 655360;      // 1024x2560
static constexpr size_t OFF_XH   = OFF_P    + 2621440;     // h [2 parity][b][640]
static constexpr size_t OFF_XZ   = OFF_XH   + 40960;       // tanh z [b][640]
static constexpr size_t OFF_SC   = OFF_XZ   + 20480;       // score[32]
static constexpr size_t OFF_GS   = OFF_SC   + 32;          // sumexp [2][32]
static constexpr size_t OFF_KEY  = OFF_GS   + 64;          // u64 key [2][32] (128 floats)
static constexpr size_t OFF_CNT  = OFF_KEY  + 128;         // 3 counters, stride 32 ints
static constexpr size_t OFF_END  = OFF_CNT  + 96;          // ~23.4 MB total

__device__ __forceinline__ float sigf(float x) { return 1.0f / (1.0f + expf(-x)); }

__device__ __forceinline__ u32 ordf(float f) {
  u32 u = __float_as_uint(f);
  return (u & 0x80000000u) ? ~u : (u | 0x80000000u);
}

__device__ __forceinline__ void wait_ge(int* cnt, int target) {
  if (threadIdx.x == 0) {
    while (__hip_atomic_load(cnt, __ATOMIC_RELAXED, __HIP_MEMORY_SCOPE_AGENT) < target)
      __builtin_amdgcn_s_sleep(2);
    __threadfence(); // agent acquire: CU-wide L1 inv + L2 inv (validated R1)
  }
  __syncthreads();
}

__device__ __forceinline__ void stage_done(int* cnt) {
  __syncthreads(); // per-wave vmcnt drain -> all block stores in L2
  if (threadIdx.x == 0)
    __hip_atomic_fetch_add(cnt, 1, __ATOMIC_RELEASE, __HIP_MEMORY_SCOPE_AGENT); // wbl2
}

// 4 rows x 4 batch register-blocked matvec over d-range [d0, d0+NQ*4).
// W4 layout: float4 at [(d>>2)*R + row] = W[row][d..d+3].
template <int R, int NQ>
__device__ __forceinline__ void mv44(const float4* __restrict__ W4q, int row0,
                                     const float* __restrict__ Xb, size_t xstr,
                                     int b0, int d0, float acc[4][4]) {
#pragma unroll 5
  for (int q = 0; q < NQ; ++q) {
    const float4* wp = W4q + (size_t)((d0 >> 2) + q) * R + row0;
    float4 w0 = wp[0], w1 = wp[1], w2 = wp[2], w3 = wp[3];
#pragma unroll
    for (int k = 0; k < 4; ++k) {
      float4 x = *(const float4*)(Xb + (size_t)(b0 + k) * xstr + d0 + q * 4);
      acc[0][k] = fmaf(w0.x, x.x, fmaf(w0.y, x.y, fmaf(w0.z, x.z, fmaf(w0.w, x.w, acc[0][k]))));
      acc[1][k] = fmaf(w1.x, x.x, fmaf(w1.y, x.y, fmaf(w1.z, x.z, fmaf(w1.w, x.w, acc[1][k]))));
      acc[2][k] = fmaf(w2.x, x.x, fmaf(w2.y, x.y, fmaf(w2.z, x.z, fmaf(w2.w, x.w, acc[2][k]))));
      acc[3][k] = fmaf(w3.x, x.x, fmaf(w3.y, x.y, fmaf(w3.z, x.z, fmaf(w3.w, x.w, acc[3][k]))));
    }
  }
}

// ---- setup kernels ----

// W[j][d] (row-major, K=640) -> WT4: float4 at (d/4)*J + j holds W[j][4q..4q+3]
__global__ __launch_bounds__(256) void k_wt4(const float* __restrict__ W,
                                             float* __restrict__ WT4, int J) {
  __shared__ float tile[64][65];
  int nj = J >> 6;
  int tj = blockIdx.x % nj, tk = blockIdx.x / nj;
  int jb = tj << 6, kb = tk << 6;
  for (int i = threadIdx.x; i < 4096; i += 256) {
    int d = i & 63, j = i >> 6;
    tile[j][d] = W[(size_t)(jb + j) * DD + (kb + d)];
  }
  __syncthreads();
  for (int i = threadIdx.x; i < 1024; i += 256) {
    int j = i & 63, q = i >> 6;
    float4 v = make_float4(tile[j][q * 4], tile[j][q * 4 + 1], tile[j][q * 4 + 2],
                           tile[j][q * 4 + 3]);
    ((float4*)WT4)[(size_t)((kb >> 2) + q) * J + (jb + j)] = v;
  }
}

// P[v][g] = sum_d E[v][d] * Wih[g][d]
__global__ __launch_bounds__(256) void k_pgemm(const float* __restrict__ E,
                                               const float* __restrict__ Wih,
                                               float* __restrict__ P) {
  __shared__ float As[16][65], Bs[16][65];
  int vt = blockIdx.x & 15, gt = blockIdx.x >> 4;
  int vb = vt << 6, gb = gt << 6;
  int tv = threadIdx.x & 15, tg = threadIdx.x >> 4;
  float acc[4][4] = {};
  for (int kb = 0; kb < DD; kb += 16) {
    for (int i = threadIdx.x; i < 1024; i += 256) {
      int k = i & 15, x = i >> 4;
      As[k][x] = E[(size_t)(vb + x) * DD + kb + k];
      Bs[k][x] = Wih[(size_t)(gb + x) * DD + kb + k];
    }
    __syncthreads();
#pragma unroll
    for (int k = 0; k < 16; ++k) {
      float av[4], bv[4];
#pragma unroll
      for (int i = 0; i < 4; ++i) av[i] = As[k][tv * 4 + i];
#pragma unroll
      for (int j = 0; j < 4; ++j) bv[j] = Bs[k][tg * 4 + j];
#pragma unroll
      for (int i = 0; i < 4; ++i)
#pragma unroll
        for (int j = 0; j < 4; ++j) acc[i][j] = fmaf(av[i], bv[j], acc[i][j]);
    }
    __syncthreads();
  }
#pragma unroll
  for (int i = 0; i < 4; ++i)
#pragma unroll
    for (int j = 0; j < 4; ++j)
      P[(size_t)(vb + tv * 4 + i) * GG + gb + tg * 4 + j] = acc[i][j];
}

// initial LSTM step: x0 = E[0], h0=c0=0 -> h1 identical for all b; write XH parity 0.
__global__ __launch_bounds__(256) void k_init(float* __restrict__ ws,
                                              const float* __restrict__ bl) {
  const float* P = ws + OFF_P;
  float* XH0 = ws + OFF_XH;
  int tid = blockIdx.x * 256 + threadIdx.x;
  if (tid < DD) {
    int j = tid;
    float gi = P[j] + bl[j];
    float gg = P[1280 + j] + bl[1280 + j];
    float go = P[1920 + j] + bl[1920 + j];
    float c1 = sigf(gi) * tanhf(gg);
    float h1 = sigf(go) * tanhf(c1);
    for (int b = 0; b < 32; ++b) XH0[b * DD + j] = h1;
  }
  if (blockIdx.x == 3) {
    int t = threadIdx.x;
    if (t < 64) {
      ((u64*)(ws + OFF_KEY))[t & 63] = 0ull;
      (ws + OFF_GS)[t] = 0.f;
    }
    if (t < 32) (ws + OFF_SC)[t] = 0.f;
    if (t < 3) ((int*)(ws + OFF_CNT))[t * 32] = 0;
  }
}

// ---- persistent decode ----
__global__ __launch_bounds__(256, 2) void k_decode(float* __restrict__ ws,
                                                   const float* __restrict__ tn,
                                                   const float* __restrict__ bl,
                                                   const float* __restrict__ bj,
                                                   const float* __restrict__ bo,
                                                   float* __restrict__ out) {
  const float* WTN = ws + OFF_WTN;
  const float* WPN = ws + OFF_WPN;
  const float* WHH = ws + OFF_WHH;
  const float* WOUT = ws + OFF_WOUT;
  const float* P = ws + OFF_P;
  float* XH = ws + OFF_XH;
  float* XZ = ws + OFF_XZ;
  float* SCg = ws + OFF_SC;
  float* GS = ws + OFF_GS;
  u64* KEY = (u64*)(ws + OFF_KEY);
  int* CNT = (int*)(ws + OFF_CNT);
  int* cntA = CNT + 0;
  int* cntL = CNT + 32;
  int* cntC = CNT + 64;

  __shared__ float red[4224];     // 16.5 KB: [dsplit][row][33]
  __shared__ float aux[16 * 33];  // combined rows / logit tile
  __shared__ float c_lds[4][32];  // C: persistent cell state
  __shared__ float sc_lds[32];
  __shared__ int tok_lds[32], nb_lds[32], lt_lds[32];

  const int bid = blockIdx.x, tid = threadIdx.x;

  if (bid < NA) {
    // ---- stage A: XZ = tanh(W_tn.tn_t + W_pn.h + b_joint), 8 j rows/block ----
    const int j0 = bid * 8;
    const int dq = tid >> 4;            // 16 d-groups of 40
    const int rq = (tid >> 3) & 1, b0 = (tid & 7) * 4;
    const int d0 = dq * 40, row0 = j0 + rq * 4;
    for (int t = 0; t < TT; ++t) {
      wait_ge(cntC, NC * t);
      const float* xh = XH + (size_t)(t & 1) * 20480;
      float acc[4][4] = {};
      mv44<DD, 10>((const float4*)WTN, row0, tn + (size_t)t * DD, (size_t)TT * DD, b0, d0, acc);
      mv44<DD, 10>((const float4*)WPN, row0, xh, DD, b0, d0, acc);
#pragma unroll
      for (int i = 0; i < 4; ++i)
#pragma unroll
        for (int k = 0; k < 4; ++k) red[(dq * 8 + rq * 4 + i) * 33 + b0 + k] = acc[i][k];
      __syncthreads();
      {
        int r = tid >> 5, b = tid & 31;
        float s = 0.f;
#pragma unroll
        for (int d2 = 0; d2 < 16; ++d2) s += red[(d2 * 8 + r) * 33 + b];
        int j = j0 + r;
        XZ[b * DD + j] = tanhf(s + bj[j]);
      }
      stage_done(cntA);
    }
  } else if (bid < NA + NL) {
    // ---- stage L: logits tile (16 v) + per-b argmax key / sumexp atomics ----
    const int v0 = (bid - NA) * 16;
    const int dq = tid >> 5;            // 8 d-groups of 80
    const int rq = (tid >> 3) & 3, b0 = (tid & 7) * 4;
    const int d0 = dq * 80, row0 = v0 + rq * 4;
    for (int t = 0; t < TT; ++t) {
      wait_ge(cntA, NA * (t + 1));
      float acc[4][4] = {};
      mv44<VV, 20>((const float4*)WOUT, row0, XZ, DD, b0, d0, acc);
#pragma unroll
      for (int i = 0; i < 4; ++i)
#pragma unroll
        for (int k = 0; k < 4; ++k) red[(dq * 16 + rq * 4 + i) * 33 + b0 + k] = acc[i][k];
      __syncthreads();
#pragma unroll
      for (int o = tid; o < 512; o += 256) {
        int r = o >> 5, b = o & 31;
        float s = bo[v0 + r];
#pragma unroll
        for (int d2 = 0; d2 < 8; ++d2) s += red[(d2 * 16 + r) * 33 + b];
        aux[r * 33 + b] = s;
      }
      __syncthreads();
      if (tid < 32) {
        int b = tid, par = t & 1;
        float m = -1e30f, se = 0.f;
        int vbest = 0;
#pragma unroll
        for (int r = 0; r < 16; ++r) {
          float x = aux[r * 33 + b];
          se += expf(x);
          if (x > m) { m = x; vbest = r; } // strict > => first occurrence
        }
        u64 key = ((u64)ordf(m) << 32) | (u64)(0xFFFFFFFFu - (u32)(v0 + vbest));
        atomicMax(&KEY[par * 32 + b], key);
        atomicAdd(&GS[par * 32 + b], se);
      }
      stage_done(cntL);
    }
  } else {
    // ---- stage C: gates = W_hh.h (4 j x 4 gates), then decode + LSTM elementwise ----
    const int cb = bid - (NA + NL), j0 = cb * 4;
    const int dq = tid >> 5;            // 8 d-groups of 80
    const int rq = (tid >> 3) & 3, b0 = (tid & 7) * 4; // rq = gate
    const int d0 = dq * 80, row0 = rq * DD + j0;
    // init persistent state: c1 from P[0] (h0=c0=0)
    if (tid < 128) {
      int jl = tid >> 5, b = tid & 31, j = j0 + jl;
      float gi = P[j] + bl[j];
      float gg = P[1280 + j] + bl[1280 + j];
      c_lds[jl][b] = sigf(gi) * tanhf(gg);
    }
    if (tid < 32) { lt_lds[tid] = 0; sc_lds[tid] = 0.f; }
    __syncthreads();
    for (int t = 0; t < TT; ++t) {
      const int par = t & 1;
      wait_ge(cntC, NC * t);
      if (cb == 0 && tid < 32) { // zero buffers for step t+1 (all t-1 readers done)
        KEY[(1 - par) * 32 + tid] = 0ull;
        GS[(1 - par) * 32 + tid] = 0.f;
      }
      const float* xh = XH + (size_t)par * 20480;
      float acc[4][4] = {};
      mv44<GG, 20>((const float4*)WHH, row0, xh, DD, b0, d0, acc);
#pragma unroll
      for (int i = 0; i < 4; ++i)
#pragma unroll
        for (int k = 0; k < 4; ++k) red[(dq * 16 + rq * 4 + i) * 33 + b0 + k] = acc[i][k];
      __syncthreads();
#pragma unroll
      for (int o = tid; o < 512; o += 256) {
        int r = o >> 5, b = o & 31;
        float s = 0.f;
#pragma unroll
        for (int d2 = 0; d2 < 8; ++d2) s += red[(d2 * 16 + r) * 33 + b];
        aux[r * 33 + b] = s;
      }
      wait_ge(cntL, NL * (t + 1)); // has __syncthreads
      if (tid < 32) {
        int b = tid;
        u64 key = __hip_atomic_load(&KEY[par * 32 + b], __ATOMIC_RELAXED, __HIP_MEMORY_SCOPE_AGENT);
        u32 ou = (u32)(key >> 32);
        u32 fb = (ou & 0x80000000u) ? (ou & 0x7FFFFFFFu) : ~ou;
        float m = __uint_as_float(fb);
        int v = (int)(0xFFFFFFFFu - (u32)(key & 0xFFFFFFFFull));
        int nb = (v != 0) ? 1 : 0;
        int tok = nb ? v : lt_lds[b];
        lt_lds[b] = tok;
        tok_lds[b] = tok;
        nb_lds[b] = nb;
        if (cb == 0) {
          float S = __hip_atomic_load(&GS[par * 32 + b], __ATOMIC_RELAXED, __HIP_MEMORY_SCOPE_AGENT);
          float lp = m - logf(S); // logits bounded: no max-shift needed
          if (nb) sc_lds[b] += lp;
          out[(size_t)b * TT + t] = nb ? (float)v : 0.0f;
          if (t == TT - 1) SCg[b] = sc_lds[b];
        }
      }
      __syncthreads();
      if (tid < 128) {
        int jl = tid >> 5, b = tid & 31, j = j0 + jl;
        float hn;
        if (nb_lds[b]) {
          const float* Pr = P + (size_t)tok_lds[b] * GG;
          float gi = aux[(0 + jl) * 33 + b] + Pr[j] + bl[j];
          float gf = aux[(4 + jl) * 33 + b] + Pr[640 + j] + bl[640 + j];
          float gg = aux[(8 + jl) * 33 + b] + Pr[1280 + j] + bl[1280 + j];
          float go = aux[(12 + jl) * 33 + b] + Pr[1920 + j] + bl[1920 + j];
          float c = c_lds[jl][b];
          float cn = sigf(gf) * c + sigf(gi) * tanhf(gg);
          hn = sigf(go) * tanhf(cn);
          c_lds[jl][b] = cn;
        } else {
          hn = xh[b * DD + j];
        }
        XH[(size_t)(1 - par) * 20480 + b * DD + j] = hn;
      }
      stage_done(cntC);
    }
  }
}

__global__ __launch_bounds__(64) void k_final(const float* __restrict__ ws,
                                              float* __restrict__ out) {
  __shared__ float sh[32];
  int t = threadIdx.x;
  if (t < 32) {
    float s = ws[OFF_SC + t];
    out[32000 + t] = s;
    sh[t] = expf(s);
  }
  __syncthreads();
  if (t == 0) {
    float a = 0.f;
    for (int i = 0; i < 32; ++i) a += sh[i];
    out[32032] = a / 32.0f;
  }
}

extern "C" void kernel_launch(void* const* d_in, const int* in_sizes, int n_in,
                              void* d_out, int out_size, void* d_ws, size_t ws_size,
                              hipStream_t stream) {
  const float* tn = (const float*)d_in[0];
  const float* E = (const float*)d_in[1];
  const float* Wih = (const float*)d_in[2];
  const float* Whh = (const float*)d_in[3];
  const float* bl = (const float*)d_in[4];
  const float* Wtn = (const float*)d_in[5];
  const float* Wpn = (const float*)d_in[6];
  const float* bj = (const float*)d_in[7];
  const float* Wout = (const float*)d_in[8];
  const float* bo = (const float*)d_in[9];
  float* ws = (float*)d_ws;
  float* out = (float*)d_out;

  k_wt4<<<100, 256, 0, stream>>>(Wtn, ws + OFF_WTN, DD);
  k_wt4<<<100, 256, 0, stream>>>(Wpn, ws + OFF_WPN, DD);
  k_wt4<<<400, 256, 0, stream>>>(Whh, ws + OFF_WHH, GG);
  k_wt4<<<160, 256, 0, stream>>>(Wout, ws + OFF_WOUT, VV);
  k_pgemm<<<640, 256, 0, stream>>>(E, Wih, ws + OFF_P);
  k_init<<<4, 256, 0, stream>>>(ws, bl);
  k_decode<<<NBLK, 256, 0, stream>>>(ws, tn, bl, bj, bo, out);
  k_final<<<1, 64, 0, stream>>>(ws, out);
}

// Round 3
// 51849.164 us; speedup vs baseline: 2.5588x; 1.4044x over previous
//
#include <hip/hip_runtime.h>
#include <stdint.h>

// Transducer greedy decode, persistent 3-stage pipeline, LIGHTWEIGHT SYNC.
// B=32 T=1000 D=640 V=1024, gates=4*640=2560.  out_pn == h.
// R2 post-mortem: heavy agent fences (buffer_wbl2 + L1/L2 inv) cost ~23us per
// handoff and forced 12.3 MB/step of weight refetch through LLC. This version:
//   - cross-stage data (XH, XZ, KEY, GS, counters) via relaxed AGENT-scope
//     atomics (bypass L1/L2, serviced at coherent LLC) -> no cache-wide
//     fences needed at all.
//   - release = __syncthreads() (emits s_waitcnt vmcnt(0) before s_barrier,
//     so coherent stores are retired at LLC) + relaxed agent counter add.
//   - weights/tn/P immutable -> normal cached loads; with no invalidates they
//     stay L2-resident across all 1000 steps.
// Stages (224 blocks x 256 thr, 1 block/CU):
//   A (80 blk, 8 j):  XZ = tanh(W_tn.tn_t + W_pn.h + b_joint)
//   L (64 blk, 16 v): logits; per-b atomicMax(key) + atomicAdd(sumexp)
//   C (80 blk, 8 j x 4 gates, 2 passes): gates = W_hh.h; decode + LSTM elem
// Chain per step: C(t-1) -> A(t) -> L(t) -> C-elem(t).

typedef unsigned long long u64;
typedef uint32_t u32;

#define TT 1000
#define DD 640
#define GG 2560
#define VV 1024

#define NA 80
#define NL 64
#define NC 80
#define NBLK (NA + NL + NC) // 224

// ws layout (float offsets)
static constexpr size_t OFF_WTN  = 0;                      // 640x640  WT4 layout
static constexpr size_t OFF_WPN  = OFF_WTN  + 409600;
static constexpr size_t OFF_WHH  = OFF_WPN  + 409600;      // 2560x640
static constexpr size_t OFF_WOUT = OFF_WHH  + 1638400;     // 1024x640
static constexpr size_t OFF_P    = OFF_WOUT + 655360;      // 1024x2560
static constexpr size_t OFF_XH   = OFF_P    + 2621440;     // h [2 parity][b][640]
static constexpr size_t OFF_XZ   = OFF_XH   + 40960;       // tanh z [b][640]
static constexpr size_t OFF_SC   = OFF_XZ   + 20480;       // score[32]
static constexpr size_t OFF_GS   = OFF_SC   + 32;          // sumexp [2][32]
static constexpr size_t OFF_KEY  = OFF_GS   + 64;          // u64 key [2][32]
static constexpr size_t OFF_CNT  = OFF_KEY  + 128;         // 3 counters, stride 32
static constexpr size_t OFF_END  = OFF_CNT  + 96;          // ~23.4 MB total

__device__ __forceinline__ float sigf(float x) { return 1.0f / (1.0f + expf(-x)); }

__device__ __forceinline__ u32 ordf(float f) {
  u32 u = __float_as_uint(f);
  return (u & 0x80000000u) ? ~u : (u | 0x80000000u);
}

// ---- coherent (LLC) scalar-pair access: bypasses L1/L2, no fences needed ----
__device__ __forceinline__ void cstore2(float* p, float a, float b) {
  u64 v = ((u64)__float_as_uint(b) << 32) | (u64)__float_as_uint(a);
  __hip_atomic_store((u64*)p, v, __ATOMIC_RELAXED, __HIP_MEMORY_SCOPE_AGENT);
}
__device__ __forceinline__ float2 cload2(const float* p) {
  u64 v = __hip_atomic_load((const u64*)p, __ATOMIC_RELAXED, __HIP_MEMORY_SCOPE_AGENT);
  return make_float2(__uint_as_float((u32)v), __uint_as_float((u32)(v >> 32)));
}

// wait: poll relaxed agent load (LLC). __syncthreads() after = block-wide order.
__device__ __forceinline__ void wait_ge(int* cnt, int target) {
  if (threadIdx.x == 0) {
    while (__hip_atomic_load(cnt, __ATOMIC_RELAXED, __HIP_MEMORY_SCOPE_AGENT) < target)
      __builtin_amdgcn_s_sleep(2);
  }
  __syncthreads();
}

// release: __syncthreads drains every wave's vmcnt (coherent stores now at LLC),
// then one relaxed agent add. No wbl2, no inv.
__device__ __forceinline__ void stage_done(int* cnt) {
  __syncthreads();
  if (threadIdx.x == 0)
    __hip_atomic_fetch_add(cnt, 1, __ATOMIC_RELAXED, __HIP_MEMORY_SCOPE_AGENT);
}

// 4 rows x 4 batch matvec, NORMAL cached x loads (immutable inputs: tn).
template <int R, int NQ>
__device__ __forceinline__ void mv44n(const float4* __restrict__ W4q, int row0,
                                      const float* __restrict__ Xb, size_t xstr,
                                      int b0, int d0, float acc[4][4]) {
#pragma unroll 5
  for (int q = 0; q < NQ; ++q) {
    const float4* wp = W4q + (size_t)((d0 >> 2) + q) * R + row0;
    float4 w0 = wp[0], w1 = wp[1], w2 = wp[2], w3 = wp[3];
#pragma unroll
    for (int k = 0; k < 4; ++k) {
      float4 x = *(const float4*)(Xb + (size_t)(b0 + k) * xstr + d0 + q * 4);
      acc[0][k] = fmaf(w0.x, x.x, fmaf(w0.y, x.y, fmaf(w0.z, x.z, fmaf(w0.w, x.w, acc[0][k]))));
      acc[1][k] = fmaf(w1.x, x.x, fmaf(w1.y, x.y, fmaf(w1.z, x.z, fmaf(w1.w, x.w, acc[1][k]))));
      acc[2][k] = fmaf(w2.x, x.x, fmaf(w2.y, x.y, fmaf(w2.z, x.z, fmaf(w2.w, x.w, acc[2][k]))));
      acc[3][k] = fmaf(w3.x, x.x, fmaf(w3.y, x.y, fmaf(w3.z, x.z, fmaf(w3.w, x.w, acc[3][k]))));
    }
  }
}

// 4 rows x 4 batch matvec, COHERENT x loads (cross-stage data: XH, XZ).
template <int R, int NQ>
__device__ __forceinline__ void mv44c(const float4* __restrict__ W4q, int row0,
                                      const float* __restrict__ Xb, size_t xstr,
                                      int b0, int d0, float acc[4][4]) {
#pragma unroll 5
  for (int q = 0; q < NQ; ++q) {
    const float4* wp = W4q + (size_t)((d0 >> 2) + q) * R + row0;
    float4 w0 = wp[0], w1 = wp[1], w2 = wp[2], w3 = wp[3];
#pragma unroll
    for (int k = 0; k < 4; ++k) {
      const float* xp = Xb + (size_t)(b0 + k) * xstr + d0 + q * 4;
      float2 xa = cload2(xp);
      float2 xc = cload2(xp + 2);
      acc[0][k] = fmaf(w0.x, xa.x, fmaf(w0.y, xa.y, fmaf(w0.z, xc.x, fmaf(w0.w, xc.y, acc[0][k]))));
      acc[1][k] = fmaf(w1.x, xa.x, fmaf(w1.y, xa.y, fmaf(w1.z, xc.x, fmaf(w1.w, xc.y, acc[1][k]))));
      acc[2][k] = fmaf(w2.x, xa.x, fmaf(w2.y, xa.y, fmaf(w2.z, xc.x, fmaf(w2.w, xc.y, acc[2][k]))));
      acc[3][k] = fmaf(w3.x, xa.x, fmaf(w3.y, xa.y, fmaf(w3.z, xc.x, fmaf(w3.w, xc.y, acc[3][k]))));
    }
  }
}

// ---- setup kernels ----

// W[j][d] (row-major, K=640) -> WT4: float4 at (d/4)*J + j holds W[j][4q..4q+3]
__global__ __launch_bounds__(256) void k_wt4(const float* __restrict__ W,
                                             float* __restrict__ WT4, int J) {
  __shared__ float tile[64][65];
  int nj = J >> 6;
  int tj = blockIdx.x % nj, tk = blockIdx.x / nj;
  int jb = tj << 6, kb = tk << 6;
  for (int i = threadIdx.x; i < 4096; i += 256) {
    int d = i & 63, j = i >> 6;
    tile[j][d] = W[(size_t)(jb + j) * DD + (kb + d)];
  }
  __syncthreads();
  for (int i = threadIdx.x; i < 1024; i += 256) {
    int j = i & 63, q = i >> 6;
    float4 v = make_float4(tile[j][q * 4], tile[j][q * 4 + 1], tile[j][q * 4 + 2],
                           tile[j][q * 4 + 3]);
    ((float4*)WT4)[(size_t)((kb >> 2) + q) * J + (jb + j)] = v;
  }
}

// P[v][g] = sum_d E[v][d] * Wih[g][d]
__global__ __launch_bounds__(256) void k_pgemm(const float* __restrict__ E,
                                               const float* __restrict__ Wih,
                                               float* __restrict__ P) {
  __shared__ float As[16][65], Bs[16][65];
  int vt = blockIdx.x & 15, gt = blockIdx.x >> 4;
  int vb = vt << 6, gb = gt << 6;
  int tv = threadIdx.x & 15, tg = threadIdx.x >> 4;
  float acc[4][4] = {};
  for (int kb = 0; kb < DD; kb += 16) {
    for (int i = threadIdx.x; i < 1024; i += 256) {
      int k = i & 15, x = i >> 4;
      As[k][x] = E[(size_t)(vb + x) * DD + kb + k];
      Bs[k][x] = Wih[(size_t)(gb + x) * DD + kb + k];
    }
    __syncthreads();
#pragma unroll
    for (int k = 0; k < 16; ++k) {
      float av[4], bv[4];
#pragma unroll
      for (int i = 0; i < 4; ++i) av[i] = As[k][tv * 4 + i];
#pragma unroll
      for (int j = 0; j < 4; ++j) bv[j] = Bs[k][tg * 4 + j];
#pragma unroll
      for (int i = 0; i < 4; ++i)
#pragma unroll
        for (int j = 0; j < 4; ++j) acc[i][j] = fmaf(av[i], bv[j], acc[i][j]);
    }
    __syncthreads();
  }
#pragma unroll
  for (int i = 0; i < 4; ++i)
#pragma unroll
    for (int j = 0; j < 4; ++j)
      P[(size_t)(vb + tv * 4 + i) * GG + gb + tg * 4 + j] = acc[i][j];
}

// initial LSTM step: x0 = E[0], h0=c0=0 -> h1 identical for all b; XH parity 0.
__global__ __launch_bounds__(256) void k_init(float* __restrict__ ws,
                                              const float* __restrict__ bl) {
  const float* P = ws + OFF_P;
  float* XH0 = ws + OFF_XH;
  int tid = blockIdx.x * 256 + threadIdx.x;
  if (tid < DD) {
    int j = tid;
    float gi = P[j] + bl[j];
    float gg = P[1280 + j] + bl[1280 + j];
    float go = P[1920 + j] + bl[1920 + j];
    float c1 = sigf(gi) * tanhf(gg);
    float h1 = sigf(go) * tanhf(c1);
    for (int b = 0; b < 32; ++b) XH0[b * DD + j] = h1;
  }
  if (blockIdx.x == 3) {
    int t = threadIdx.x;
    if (t < 64) {
      ((u64*)(ws + OFF_KEY))[t] = 0ull;
      (ws + OFF_GS)[t] = 0.f;
    }
    if (t < 32) (ws + OFF_SC)[t] = 0.f;
    if (t < 3) ((int*)(ws + OFF_CNT))[t * 32] = 0;
  }
}

// ---- persistent decode ----
__global__ __launch_bounds__(256, 1) void k_decode(float* __restrict__ ws,
                                                   const float* __restrict__ tn,
                                                   const float* __restrict__ bl,
                                                   const float* __restrict__ bj,
                                                   const float* __restrict__ bo,
                                                   float* __restrict__ out) {
  const float* WTN = ws + OFF_WTN;
  const float* WPN = ws + OFF_WPN;
  const float* WHH = ws + OFF_WHH;
  const float* WOUT = ws + OFF_WOUT;
  const float* P = ws + OFF_P;
  float* XH = ws + OFF_XH;
  float* XZ = ws + OFF_XZ;
  float* SCg = ws + OFF_SC;
  float* GS = ws + OFF_GS;
  u64* KEY = (u64*)(ws + OFF_KEY);
  int* CNT = (int*)(ws + OFF_CNT);
  int* cntA = CNT + 0;
  int* cntL = CNT + 32;
  int* cntC = CNT + 64;

  __shared__ float red[4224];       // 16.5 KB partial sums [dsplit*rows][33]
  __shared__ float aux[16 * 33];    // combined rows
  __shared__ float gl[32 * 33];     // C: gates [g*8+jl][b]
  __shared__ float c_lds[8][33];    // C: cell state
  __shared__ float h_lds[8][33];    // C: h slice (for nb==0 carry + pack)
  __shared__ float sc_lds[32];
  __shared__ int tok_lds[32], nb_lds[32], lt_lds[32];

  const int bid = blockIdx.x, tid = threadIdx.x;

  if (bid < NA) {
    // ---- stage A: XZ = tanh(W_tn.tn_t + W_pn.h + b_joint), 8 j rows ----
    const int j0 = bid * 8;
    const int dq = tid >> 4;            // 16 d-groups of 40
    const int rq = (tid >> 3) & 1, b0 = (tid & 7) * 4;
    const int d0 = dq * 40, row0 = j0 + rq * 4;
    for (int t = 0; t < TT; ++t) {
      wait_ge(cntC, NC * t);
      const float* xh = XH + (size_t)(t & 1) * 20480;
      float acc[4][4] = {};
      mv44n<DD, 10>((const float4*)WTN, row0, tn + (size_t)t * DD, (size_t)TT * DD, b0, d0, acc);
      mv44c<DD, 10>((const float4*)WPN, row0, xh, DD, b0, d0, acc);
#pragma unroll
      for (int i = 0; i < 4; ++i)
#pragma unroll
        for (int k = 0; k < 4; ++k) red[(dq * 8 + rq * 4 + i) * 33 + b0 + k] = acc[i][k];
      __syncthreads();
      {
        int r = tid >> 5, b = tid & 31;
        float s = 0.f;
#pragma unroll
        for (int d2 = 0; d2 < 16; ++d2) s += red[(d2 * 8 + r) * 33 + b];
        aux[r * 33 + b] = tanhf(s + bj[j0 + r]);
      }
      __syncthreads();
      if (tid < 128) {
        int jp = tid >> 5, b = tid & 31;
        cstore2(XZ + (size_t)b * DD + j0 + jp * 2, aux[(jp * 2) * 33 + b],
                aux[(jp * 2 + 1) * 33 + b]);
      }
      stage_done(cntA);
    }
  } else if (bid < NA + NL) {
    // ---- stage L: logits tile (16 v) + per-b argmax key / sumexp atomics ----
    const int v0 = (bid - NA) * 16;
    const int dq = tid >> 5;            // 8 d-groups of 80
    const int rq = (tid >> 3) & 3, b0 = (tid & 7) * 4;
    const int d0 = dq * 80, row0 = v0 + rq * 4;
    for (int t = 0; t < TT; ++t) {
      wait_ge(cntA, NA * (t + 1));
      float acc[4][4] = {};
      mv44c<VV, 20>((const float4*)WOUT, row0, XZ, DD, b0, d0, acc);
#pragma unroll
      for (int i = 0; i < 4; ++i)
#pragma unroll
        for (int k = 0; k < 4; ++k) red[(dq * 16 + rq * 4 + i) * 33 + b0 + k] = acc[i][k];
      __syncthreads();
#pragma unroll
      for (int o = tid; o < 512; o += 256) {
        int r = o >> 5, b = o & 31;
        float s = bo[v0 + r];
#pragma unroll
        for (int d2 = 0; d2 < 8; ++d2) s += red[(d2 * 16 + r) * 33 + b];
        aux[r * 33 + b] = s;
      }
      __syncthreads();
      if (tid < 32) {
        int b = tid, par = t & 1;
        float m = -1e30f, se = 0.f;
        int vbest = 0;
#pragma unroll
        for (int r = 0; r < 16; ++r) {
          float x = aux[r * 33 + b];
          se += expf(x);
          if (x > m) { m = x; vbest = r; } // strict > => first occurrence
        }
        u64 key = ((u64)ordf(m) << 32) | (u64)(0xFFFFFFFFu - (u32)(v0 + vbest));
        atomicMax(&KEY[par * 32 + b], key);  // device-scope -> LLC
        atomicAdd(&GS[par * 32 + b], se);
      }
      stage_done(cntL);
    }
  } else {
    // ---- stage C: gates = W_hh.h (8 j x 4 gates, two 16-row passes),
    //      then decode argmax + LSTM elementwise ----
    const int cb = bid - (NA + NL), j0 = cb * 8;
    const int dq = tid >> 5;            // 8 d-groups of 80
    const int rq = (tid >> 3) & 3, b0 = (tid & 7) * 4;
    const int d0 = dq * 80;
    // init persistent state from P[0] (h0=c0=0)
    {
      int jl = tid >> 5, b = tid & 31, j = j0 + jl;
      float gi = P[j] + bl[j];
      float gg = P[1280 + j] + bl[1280 + j];
      float go = P[1920 + j] + bl[1920 + j];
      float c1 = sigf(gi) * tanhf(gg);
      c_lds[jl][b] = c1;
      h_lds[jl][b] = sigf(go) * tanhf(c1);
    }
    if (tid < 32) { lt_lds[tid] = 0; sc_lds[tid] = 0.f; }
    __syncthreads();
    for (int t = 0; t < TT; ++t) {
      const int par = t & 1;
      wait_ge(cntC, NC * t);
      if (cb == 0 && tid < 32) { // reset buffers for step t+1 (readers of t-1 done)
        __hip_atomic_store(&KEY[(1 - par) * 32 + tid], 0ull, __ATOMIC_RELAXED,
                           __HIP_MEMORY_SCOPE_AGENT);
        __hip_atomic_store(&GS[(1 - par) * 32 + tid], 0.f, __ATOMIC_RELAXED,
                           __HIP_MEMORY_SCOPE_AGENT);
      }
      const float* xh = XH + (size_t)par * 20480;
#pragma unroll
      for (int p = 0; p < 2; ++p) {
        const int row0 = (2 * p + (rq >> 1)) * DD + j0 + (rq & 1) * 4;
        float acc[4][4] = {};
        mv44c<GG, 20>((const float4*)WHH, row0, xh, DD, b0, d0, acc);
#pragma unroll
        for (int i = 0; i < 4; ++i)
#pragma unroll
          for (int k = 0; k < 4; ++k) red[(dq * 16 + rq * 4 + i) * 33 + b0 + k] = acc[i][k];
        __syncthreads();
#pragma unroll
        for (int o = tid; o < 512; o += 256) {
          int r16 = o >> 5, b = o & 31;
          float s = 0.f;
#pragma unroll
          for (int d2 = 0; d2 < 8; ++d2) s += red[(d2 * 16 + r16) * 33 + b];
          int gate = 2 * p + (r16 >> 3);
          int jl = ((r16 >> 2) & 1) * 4 + (r16 & 3);
          gl[(gate * 8 + jl) * 33 + b] = s;
        }
        if (p == 0) __syncthreads(); // red reused by pass 1
      }
      wait_ge(cntL, NL * (t + 1)); // has __syncthreads -> gl visible too
      if (tid < 32) {
        int b = tid;
        u64 key = __hip_atomic_load(&KEY[par * 32 + b], __ATOMIC_RELAXED,
                                    __HIP_MEMORY_SCOPE_AGENT);
        u32 ou = (u32)(key >> 32);
        u32 fb = (ou & 0x80000000u) ? (ou & 0x7FFFFFFFu) : ~ou;
        float m = __uint_as_float(fb);
        int v = (int)(0xFFFFFFFFu - (u32)(key & 0xFFFFFFFFull));
        int nb = (v != 0) ? 1 : 0;
        int tok = nb ? v : lt_lds[b];
        lt_lds[b] = tok;
        tok_lds[b] = tok;
        nb_lds[b] = nb;
        if (cb == 0) {
          float S = __hip_atomic_load(&GS[par * 32 + b], __ATOMIC_RELAXED,
                                      __HIP_MEMORY_SCOPE_AGENT);
          float lp = m - logf(S); // logits bounded: no max-shift needed
          if (nb) sc_lds[b] += lp;
          out[(size_t)b * TT + t] = nb ? (float)v : 0.0f;
          if (t == TT - 1) SCg[b] = sc_lds[b];
        }
      }
      __syncthreads();
      {
        int jl = tid >> 5, b = tid & 31, j = j0 + jl;
        if (nb_lds[b]) {
          const float* Pr = P + (size_t)tok_lds[b] * GG;
          float gi = gl[(0 * 8 + jl) * 33 + b] + Pr[j] + bl[j];
          float gf = gl[(1 * 8 + jl) * 33 + b] + Pr[640 + j] + bl[640 + j];
          float gg = gl[(2 * 8 + jl) * 33 + b] + Pr[1280 + j] + bl[1280 + j];
          float go = gl[(3 * 8 + jl) * 33 + b] + Pr[1920 + j] + bl[1920 + j];
          float c = c_lds[jl][b];
          float cn = sigf(gf) * c + sigf(gi) * tanhf(gg);
          float hn = sigf(go) * tanhf(cn);
          c_lds[jl][b] = cn;
          h_lds[jl][b] = hn;
        }
      }
      __syncthreads();
      if (tid < 128) {
        int jp = tid >> 5, b = tid & 31;
        cstore2(XH + (size_t)(1 - par) * 20480 + (size_t)b * DD + j0 + jp * 2,
                h_lds[jp * 2][b], h_lds[jp * 2 + 1][b]);
      }
      stage_done(cntC);
    }
  }
}

__global__ __launch_bounds__(64) void k_final(const float* __restrict__ ws,
                                              float* __restrict__ out) {
  __shared__ float sh[32];
  int t = threadIdx.x;
  if (t < 32) {
    float s = ws[OFF_SC + t];
    out[32000 + t] = s;
    sh[t] = expf(s);
  }
  __syncthreads();
  if (t == 0) {
    float a = 0.f;
    for (int i = 0; i < 32; ++i) a += sh[i];
    out[32032] = a / 32.0f;
  }
}

extern "C" void kernel_launch(void* const* d_in, const int* in_sizes, int n_in,
                              void* d_out, int out_size, void* d_ws, size_t ws_size,
                              hipStream_t stream) {
  const float* tn = (const float*)d_in[0];
  const float* E = (const float*)d_in[1];
  const float* Wih = (const float*)d_in[2];
  const float* Whh = (const float*)d_in[3];
  const float* bl = (const float*)d_in[4];
  const float* Wtn = (const float*)d_in[5];
  const float* Wpn = (const float*)d_in[6];
  const float* bj = (const float*)d_in[7];
  const float* Wout = (const float*)d_in[8];
  const float* bo = (const float*)d_in[9];
  float* ws = (float*)d_ws;
  float* out = (float*)d_out;

  k_wt4<<<100, 256, 0, stream>>>(Wtn, ws + OFF_WTN, DD);
  k_wt4<<<100, 256, 0, stream>>>(Wpn, ws + OFF_WPN, DD);
  k_wt4<<<400, 256, 0, stream>>>(Whh, ws + OFF_WHH, GG);
  k_wt4<<<160, 256, 0, stream>>>(Wout, ws + OFF_WOUT, VV);
  k_pgemm<<<640, 256, 0, stream>>>(E, Wih, ws + OFF_P);
  k_init<<<4, 256, 0, stream>>>(ws, bl);
  k_decode<<<NBLK, 256, 0, stream>>>(ws, tn, bl, bj, bo, out);
  k_final<<<1, 64, 0, stream>>>(ws, out);
}

// Round 4
// 36046.231 us; speedup vs baseline: 3.6805x; 1.4384x over previous
//
#include <hip/hip_runtime.h>
#include <stdint.h>

// Transducer greedy decode, persistent 3-stage pipeline, ZERO-RMW sync.
// B=32 T=1000 D=640 V=1024, gates=4*640=2560.  out_pn == h.
// R3 post-mortem: same-line RMW serialization (KEY/GS atomicMax/Add fan-in +
// counter fetch_adds) cost ~17us/handoff across three fence schemes. This
// version has NO read-modify-write operations at all:
//   - L blocks plain-store per-block (max,idx) u64 + partial sumexp to own
//     slots; C blocks tree-reduce them (coalesced reads, deterministic).
//   - stage counters -> per-block flag ints, 1 per 128B line; producers
//     plain-store t+1, consumers poll one-thread-per-flag then barrier.
//   - unique-x mapping in matvecs: coherent x loads fetched once per block.
// Stages (224 blocks x 256 thr): A(80): XZ=tanh(Wtn.tn_t+Wpn.h+bj);
// L(64): logits slots; C(80): Whh.h (2 passes) + argmax-reduce + LSTM elem.
// Chain per step: C(t-1) -> A(t) -> L(t) -> C-tail(t).

typedef unsigned long long u64;
typedef uint32_t u32;

#define TT 1000
#define DD 640
#define GG 2560
#define VV 1024

#define NA 80
#define NL 64
#define NC 80
#define NBLK (NA + NL + NC) // 224

// ws layout (float offsets)
static constexpr size_t OFF_WTN  = 0;                      // 640x640  WT4
static constexpr size_t OFF_WPN  = OFF_WTN  + 409600;
static constexpr size_t OFF_WHH  = OFF_WPN  + 409600;      // 2560x640
static constexpr size_t OFF_WOUT = OFF_WHH  + 1638400;     // 1024x640
static constexpr size_t OFF_P    = OFF_WOUT + 655360;      // 1024x2560
static constexpr size_t OFF_XH   = OFF_P    + 2621440;     // h [2 par][32][640]
static constexpr size_t OFF_XZ   = OFF_XH   + 40960;       // z [32][640]
static constexpr size_t OFF_SC   = OFF_XZ   + 20480;       // score[32]
static constexpr size_t OFF_LKEY = OFF_SC   + 32;          // u64 [32][64] slots
static constexpr size_t OFF_LSE  = OFF_LKEY + 4096;        // f32 [32][64] slots
static constexpr size_t OFF_FA   = OFF_LSE  + 2048;        // 80 flags, stride 32
static constexpr size_t OFF_FL   = OFF_FA   + 2560;        // 64 flags
static constexpr size_t OFF_FC   = OFF_FL   + 2048;        // 80 flags
static constexpr size_t OFF_END  = OFF_FC   + 2560;        // ~23.2 MB

__device__ __forceinline__ float sigf(float x) { return 1.0f / (1.0f + expf(-x)); }

__device__ __forceinline__ u32 ordf(float f) {
  u32 u = __float_as_uint(f);
  return (u & 0x80000000u) ? ~u : (u | 0x80000000u);
}

// ---- coherent (LLC) accesses: bypass L1/L2, no fences needed (R3-validated) ----
__device__ __forceinline__ void cstore2(float* p, float a, float b) {
  u64 v = ((u64)__float_as_uint(b) << 32) | (u64)__float_as_uint(a);
  __hip_atomic_store((u64*)p, v, __ATOMIC_RELAXED, __HIP_MEMORY_SCOPE_AGENT);
}
__device__ __forceinline__ float2 cload2(const float* p) {
  u64 v = __hip_atomic_load((const u64*)p, __ATOMIC_RELAXED, __HIP_MEMORY_SCOPE_AGENT);
  return make_float2(__uint_as_float((u32)v), __uint_as_float((u32)(v >> 32)));
}
__device__ __forceinline__ u64 cloadu64(const u64* p) {
  return __hip_atomic_load(p, __ATOMIC_RELAXED, __HIP_MEMORY_SCOPE_AGENT);
}
__device__ __forceinline__ void cstoreu64(u64* p, u64 v) {
  __hip_atomic_store(p, v, __ATOMIC_RELAXED, __HIP_MEMORY_SCOPE_AGENT);
}
__device__ __forceinline__ float cloadf(const float* p) {
  return __hip_atomic_load(p, __ATOMIC_RELAXED, __HIP_MEMORY_SCOPE_AGENT);
}
__device__ __forceinline__ void cstoref(float* p, float v) {
  __hip_atomic_store(p, v, __ATOMIC_RELAXED, __HIP_MEMORY_SCOPE_AGENT);
}

// poll n per-block flags (stride 32 ints = 1/line), one thread per flag.
__device__ __forceinline__ void poll_flags(const int* F, int n, int target) {
  if ((int)threadIdx.x < n) {
    while (__hip_atomic_load(F + threadIdx.x * 32, __ATOMIC_RELAXED,
                             __HIP_MEMORY_SCOPE_AGENT) < target)
      __builtin_amdgcn_s_sleep(2);
  }
  __syncthreads();
}
// release: barrier drains all waves' vmcnt (stores at LLC), then plain flag store.
__device__ __forceinline__ void set_flag(int* F, int idx, int val) {
  __syncthreads();
  if (threadIdx.x == 0)
    __hip_atomic_store(F + idx * 32, val, __ATOMIC_RELAXED, __HIP_MEMORY_SCOPE_AGENT);
}

__device__ __forceinline__ void fma4(float& a, const float4 w, const float4 x) {
  a = fmaf(w.x, x.x, fmaf(w.y, x.y, fmaf(w.z, x.z, fmaf(w.w, x.w, a))));
}
__device__ __forceinline__ void fma22(float& a, const float4 w, const float2 xa,
                                      const float2 xb) {
  a = fmaf(w.x, xa.x, fmaf(w.y, xa.y, fmaf(w.z, xb.x, fmaf(w.w, xb.y, a))));
}

// ---- setup kernels ----

// W[j][d] (row-major, K=640) -> WT4: float4 at (d/4)*J + j holds W[j][4q..4q+3]
__global__ __launch_bounds__(256) void k_wt4(const float* __restrict__ W,
                                             float* __restrict__ WT4, int J) {
  __shared__ float tile[64][65];
  int nj = J >> 6;
  int tj = blockIdx.x % nj, tk = blockIdx.x / nj;
  int jb = tj << 6, kb = tk << 6;
  for (int i = threadIdx.x; i < 4096; i += 256) {
    int d = i & 63, j = i >> 6;
    tile[j][d] = W[(size_t)(jb + j) * DD + (kb + d)];
  }
  __syncthreads();
  for (int i = threadIdx.x; i < 1024; i += 256) {
    int j = i & 63, q = i >> 6;
    float4 v = make_float4(tile[j][q * 4], tile[j][q * 4 + 1], tile[j][q * 4 + 2],
                           tile[j][q * 4 + 3]);
    ((float4*)WT4)[(size_t)((kb >> 2) + q) * J + (jb + j)] = v;
  }
}

// P[v][g] = sum_d E[v][d] * Wih[g][d]
__global__ __launch_bounds__(256) void k_pgemm(const float* __restrict__ E,
                                               const float* __restrict__ Wih,
                                               float* __restrict__ P) {
  __shared__ float As[16][65], Bs[16][65];
  int vt = blockIdx.x & 15, gt = blockIdx.x >> 4;
  int vb = vt << 6, gb = gt << 6;
  int tv = threadIdx.x & 15, tg = threadIdx.x >> 4;
  float acc[4][4] = {};
  for (int kb = 0; kb < DD; kb += 16) {
    for (int i = threadIdx.x; i < 1024; i += 256) {
      int k = i & 15, x = i >> 4;
      As[k][x] = E[(size_t)(vb + x) * DD + kb + k];
      Bs[k][x] = Wih[(size_t)(gb + x) * DD + kb + k];
    }
    __syncthreads();
#pragma unroll
    for (int k = 0; k < 16; ++k) {
      float av[4], bv[4];
#pragma unroll
      for (int i = 0; i < 4; ++i) av[i] = As[k][tv * 4 + i];
#pragma unroll
      for (int j = 0; j < 4; ++j) bv[j] = Bs[k][tg * 4 + j];
#pragma unroll
      for (int i = 0; i < 4; ++i)
#pragma unroll
        for (int j = 0; j < 4; ++j) acc[i][j] = fmaf(av[i], bv[j], acc[i][j]);
    }
    __syncthreads();
  }
#pragma unroll
  for (int i = 0; i < 4; ++i)
#pragma unroll
    for (int j = 0; j < 4; ++j)
      P[(size_t)(vb + tv * 4 + i) * GG + gb + tg * 4 + j] = acc[i][j];
}

// initial LSTM step: x0 = E[0], h0=c0=0 -> h1 identical for all b; XH parity 0.
__global__ __launch_bounds__(256) void k_init(float* __restrict__ ws,
                                              const float* __restrict__ bl) {
  const float* P = ws + OFF_P;
  float* XH0 = ws + OFF_XH;
  int tid = blockIdx.x * 256 + threadIdx.x;
  if (tid < DD) {
    int j = tid;
    float gi = P[j] + bl[j];
    float gg = P[1280 + j] + bl[1280 + j];
    float go = P[1920 + j] + bl[1920 + j];
    float c1 = sigf(gi) * tanhf(gg);
    float h1 = sigf(go) * tanhf(c1);
    for (int b = 0; b < 32; ++b) XH0[b * DD + j] = h1;
  }
  if (blockIdx.x == 3) {
    int* FA = (int*)(ws + OFF_FA);
    int* FL = (int*)(ws + OFF_FL);
    int* FC = (int*)(ws + OFF_FC);
    for (int i = threadIdx.x; i < 224; i += 256) {
      int* p = (i < 80) ? (FA + i * 32)
                        : (i < 144) ? (FL + (i - 80) * 32) : (FC + (i - 144) * 32);
      *p = 0;
    }
  }
}

// ---- persistent decode ----
__global__ __launch_bounds__(256, 1) void k_decode(float* __restrict__ ws,
                                                   const float* __restrict__ tn,
                                                   const float* __restrict__ bl,
                                                   const float* __restrict__ bj,
                                                   const float* __restrict__ bo,
                                                   float* __restrict__ out) {
  const float* WTN = ws + OFF_WTN;
  const float* WPN = ws + OFF_WPN;
  const float* WHH = ws + OFF_WHH;
  const float* WOUT = ws + OFF_WOUT;
  const float* P = ws + OFF_P;
  float* XH = ws + OFF_XH;
  float* XZ = ws + OFF_XZ;
  float* SCg = ws + OFF_SC;
  u64* LKEY = (u64*)(ws + OFF_LKEY);
  float* LSE = ws + OFF_LSE;
  int* FA = (int*)(ws + OFF_FA);
  int* FL = (int*)(ws + OFF_FL);
  int* FC = (int*)(ws + OFF_FC);

  __shared__ float red[16 * 16 * 33]; // 33.8 KB partial sums
  __shared__ float aux[32 * 33];      // A: z rows; L: logit tile; C: gates gl
  __shared__ u64 kred[32 * 9];
  __shared__ float sered[32 * 9];
  __shared__ float c_lds[8 * 33], h_lds[8 * 33];
  __shared__ float sc_lds[32];
  __shared__ int tok_lds[32], nb_lds[32], lt_lds[32];

  const int bid = blockIdx.x, tid = threadIdx.x;
  const int dq = tid >> 4, bp = tid & 15;   // 16 d-groups x 16 b-pairs
  const int d0 = dq * 40, b0 = bp * 2;

  if (bid < NA) {
    // ---- stage A: XZ = tanh(W_tn.tn_t + W_pn.h + b_joint), 8 j rows ----
    const int j0 = bid * 8;
    for (int t = 0; t < TT; ++t) {
      const int par = t & 1;
      poll_flags(FC, NC, t);
      const float* xh = XH + (size_t)par * 20480;
      const float* t0p = tn + ((size_t)b0 * TT + t) * DD;
      const float* t1p = tn + ((size_t)(b0 + 1) * TT + t) * DD;
      const float* h0p = xh + (size_t)b0 * DD;
      const float* h1p = h0p + DD;
      float acc[8][2] = {};
#pragma unroll 5
      for (int q = 0; q < 10; ++q) {
        const int d = d0 + q * 4;
        float4 x0 = *(const float4*)(t0p + d);
        float4 x1 = *(const float4*)(t1p + d);
        float2 h0a = cload2(h0p + d), h0b = cload2(h0p + d + 2);
        float2 h1a = cload2(h1p + d), h1b = cload2(h1p + d + 2);
        const float4* wt = (const float4*)WTN + (size_t)(d >> 2) * DD + j0;
        const float4* wp = (const float4*)WPN + (size_t)(d >> 2) * DD + j0;
#pragma unroll
        for (int r = 0; r < 8; ++r) {
          float4 w = wt[r];
          fma4(acc[r][0], w, x0);
          fma4(acc[r][1], w, x1);
          float4 v = wp[r];
          fma22(acc[r][0], v, h0a, h0b);
          fma22(acc[r][1], v, h1a, h1b);
        }
      }
#pragma unroll
      for (int r = 0; r < 8; ++r) {
        red[(dq * 8 + r) * 33 + b0] = acc[r][0];
        red[(dq * 8 + r) * 33 + b0 + 1] = acc[r][1];
      }
      __syncthreads();
      {
        int r = tid >> 5, b = tid & 31;
        float s = 0.f;
#pragma unroll
        for (int k = 0; k < 16; ++k) s += red[(k * 8 + r) * 33 + b];
        aux[r * 33 + b] = tanhf(s + bj[j0 + r]);
      }
      __syncthreads();
      if (tid < 128) {
        int jp = tid >> 5, b = tid & 31;
        cstore2(XZ + (size_t)b * DD + j0 + jp * 2, aux[(jp * 2) * 33 + b],
                aux[(jp * 2 + 1) * 33 + b]);
      }
      set_flag(FA, bid, t + 1);
    }
  } else if (bid < NA + NL) {
    // ---- stage L: 16-v logit tile -> per-block slots (no atomics) ----
    const int lb = bid - NA, v0 = lb * 16;
    for (int t = 0; t < TT; ++t) {
      poll_flags(FA, NA, t + 1);
      const float* z0p = XZ + (size_t)b0 * DD;
      const float* z1p = z0p + DD;
      float acc[16][2] = {};
#pragma unroll 5
      for (int q = 0; q < 10; ++q) {
        const int d = d0 + q * 4;
        float2 z0a = cload2(z0p + d), z0b = cload2(z0p + d + 2);
        float2 z1a = cload2(z1p + d), z1b = cload2(z1p + d + 2);
        const float4* wo = (const float4*)WOUT + (size_t)(d >> 2) * VV + v0;
#pragma unroll
        for (int r = 0; r < 16; ++r) {
          float4 w = wo[r];
          fma22(acc[r][0], w, z0a, z0b);
          fma22(acc[r][1], w, z1a, z1b);
        }
      }
#pragma unroll
      for (int r = 0; r < 16; ++r) {
        red[(dq * 16 + r) * 33 + b0] = acc[r][0];
        red[(dq * 16 + r) * 33 + b0 + 1] = acc[r][1];
      }
      __syncthreads();
#pragma unroll
      for (int o = tid; o < 512; o += 256) {
        int r = o >> 5, b = o & 31;
        float s = bo[v0 + r];
#pragma unroll
        for (int k = 0; k < 16; ++k) s += red[(k * 16 + r) * 33 + b];
        aux[r * 33 + b] = s;
      }
      __syncthreads();
      if (tid < 32) {
        int b = tid;
        float m = -1e30f, se = 0.f;
        int vbest = 0;
#pragma unroll
        for (int r = 0; r < 16; ++r) {
          float x = aux[r * 33 + b];
          se += expf(x);
          if (x > m) { m = x; vbest = r; } // strict > => first occurrence
        }
        u64 key = ((u64)ordf(m) << 32) | (u64)(0xFFFFFFFFu - (u32)(v0 + vbest));
        cstoreu64(&LKEY[(size_t)b * 64 + lb], key);
        cstoref(&LSE[(size_t)b * 64 + lb], se);
      }
      set_flag(FL, lb, t + 1);
    }
  } else {
    // ---- stage C: gates = W_hh.h (2 passes of 16 rows), argmax-reduce,
    //      decode, LSTM elementwise ----
    const int cb = bid - (NA + NL), j0 = cb * 8;
    {
      int jj = tid >> 5, b = tid & 31, j = j0 + jj;
      float gi = P[j] + bl[j];
      float gg = P[1280 + j] + bl[1280 + j];
      float go = P[1920 + j] + bl[1920 + j];
      float c1 = sigf(gi) * tanhf(gg);
      c_lds[jj * 33 + b] = c1;
      h_lds[jj * 33 + b] = sigf(go) * tanhf(c1);
    }
    if (tid < 32) { lt_lds[tid] = 0; sc_lds[tid] = 0.f; }
    __syncthreads();
    for (int t = 0; t < TT; ++t) {
      const int par = t & 1;
      poll_flags(FC, NC, t);
      const float* xh = XH + (size_t)par * 20480;
      const float* h0p = xh + (size_t)b0 * DD;
      const float* h1p = h0p + DD;
#pragma unroll
      for (int p = 0; p < 2; ++p) {
        float acc[16][2] = {};
#pragma unroll 5
        for (int q = 0; q < 10; ++q) {
          const int d = d0 + q * 4;
          float2 h0a = cload2(h0p + d), h0b = cload2(h0p + d + 2);
          float2 h1a = cload2(h1p + d), h1b = cload2(h1p + d + 2);
          const float4* wa =
              (const float4*)WHH + (size_t)(d >> 2) * GG + (2 * p) * DD + j0;
          const float4* wb = wa + DD;
#pragma unroll
          for (int jj = 0; jj < 8; ++jj) {
            float4 w = wa[jj];
            fma22(acc[jj][0], w, h0a, h0b);
            fma22(acc[jj][1], w, h1a, h1b);
            float4 v = wb[jj];
            fma22(acc[8 + jj][0], v, h0a, h0b);
            fma22(acc[8 + jj][1], v, h1a, h1b);
          }
        }
#pragma unroll
        for (int r = 0; r < 16; ++r) {
          red[(dq * 16 + r) * 33 + b0] = acc[r][0];
          red[(dq * 16 + r) * 33 + b0 + 1] = acc[r][1];
        }
        __syncthreads();
#pragma unroll
        for (int o = tid; o < 512; o += 256) {
          int r = o >> 5, b = o & 31;
          float s = 0.f;
#pragma unroll
          for (int k = 0; k < 16; ++k) s += red[(k * 16 + r) * 33 + b];
          int g = 2 * p + (r >> 3), jj = r & 7;
          aux[(g * 8 + jj) * 33 + b] = s; // gl
        }
        __syncthreads();
      }
      poll_flags(FL, NL, t + 1);
      // tree-reduce per-block argmax/sumexp slots (coalesced, deterministic)
      {
        int b = tid >> 3, ch = tid & 7;
        const u64* kp = LKEY + (size_t)b * 64 + ch * 8;
        u64 km = 0;
#pragma unroll
        for (int i = 0; i < 8; ++i) {
          u64 x = cloadu64(kp + i);
          km = x > km ? x : km;
        }
        kred[b * 9 + ch] = km;
        if (cb == 0) {
          const float* sp = LSE + (size_t)b * 64 + ch * 8;
          float ss = 0.f;
#pragma unroll
          for (int i = 0; i < 8; ++i) ss += cloadf(sp + i);
          sered[b * 9 + ch] = ss;
        }
      }
      __syncthreads();
      if (tid < 32) {
        int b = tid;
        u64 km = 0;
#pragma unroll
        for (int ch = 0; ch < 8; ++ch) {
          u64 x = kred[b * 9 + ch];
          km = x > km ? x : km;
        }
        u32 ou = (u32)(km >> 32);
        u32 fb = (ou & 0x80000000u) ? (ou & 0x7FFFFFFFu) : ~ou;
        float m = __uint_as_float(fb);
        int v = (int)(0xFFFFFFFFu - (u32)(km & 0xFFFFFFFFull));
        int nb = (v != 0) ? 1 : 0;
        int tok = nb ? v : lt_lds[b];
        lt_lds[b] = tok;
        tok_lds[b] = tok;
        nb_lds[b] = nb;
        if (cb == 0) {
          float S = 0.f;
#pragma unroll
          for (int ch = 0; ch < 8; ++ch) S += sered[b * 9 + ch];
          float lp = m - logf(S); // logits bounded: no max-shift needed
          if (nb) sc_lds[b] += lp;
          out[(size_t)b * TT + t] = nb ? (float)v : 0.0f;
          if (t == TT - 1) SCg[b] = sc_lds[b];
        }
      }
      __syncthreads();
      {
        int jj = tid >> 5, b = tid & 31, j = j0 + jj;
        if (nb_lds[b]) {
          const float* Pr = P + (size_t)tok_lds[b] * GG;
          float gi = aux[(0 + jj) * 33 + b] + Pr[j] + bl[j];
          float gf = aux[(8 + jj) * 33 + b] + Pr[640 + j] + bl[640 + j];
          float gg = aux[(16 + jj) * 33 + b] + Pr[1280 + j] + bl[1280 + j];
          float go = aux[(24 + jj) * 33 + b] + Pr[1920 + j] + bl[1920 + j];
          float c = c_lds[jj * 33 + b];
          float cn = sigf(gf) * c + sigf(gi) * tanhf(gg);
          float hn = sigf(go) * tanhf(cn);
          c_lds[jj * 33 + b] = cn;
          h_lds[jj * 33 + b] = hn;
        }
      }
      __syncthreads();
      if (tid < 128) {
        int jp = tid >> 5, b = tid & 31;
        cstore2(XH + (size_t)(1 - par) * 20480 + (size_t)b * DD + j0 + jp * 2,
                h_lds[(jp * 2) * 33 + b], h_lds[(jp * 2 + 1) * 33 + b]);
      }
      set_flag(FC, cb, t + 1);
    }
  }
}

__global__ __launch_bounds__(64) void k_final(const float* __restrict__ ws,
                                              float* __restrict__ out) {
  __shared__ float sh[32];
  int t = threadIdx.x;
  if (t < 32) {
    float s = ws[OFF_SC + t];
    out[32000 + t] = s;
    sh[t] = expf(s);
  }
  __syncthreads();
  if (t == 0) {
    float a = 0.f;
    for (int i = 0; i < 32; ++i) a += sh[i];
    out[32032] = a / 32.0f;
  }
}

extern "C" void kernel_launch(void* const* d_in, const int* in_sizes, int n_in,
                              void* d_out, int out_size, void* d_ws, size_t ws_size,
                              hipStream_t stream) {
  const float* tn = (const float*)d_in[0];
  const float* E = (const float*)d_in[1];
  const float* Wih = (const float*)d_in[2];
  const float* Whh = (const float*)d_in[3];
  const float* bl = (const float*)d_in[4];
  const float* Wtn = (const float*)d_in[5];
  const float* Wpn = (const float*)d_in[6];
  const float* bj = (const float*)d_in[7];
  const float* Wout = (const float*)d_in[8];
  const float* bo = (const float*)d_in[9];
  float* ws = (float*)d_ws;
  float* out = (float*)d_out;

  k_wt4<<<100, 256, 0, stream>>>(Wtn, ws + OFF_WTN, DD);
  k_wt4<<<100, 256, 0, stream>>>(Wpn, ws + OFF_WPN, DD);
  k_wt4<<<400, 256, 0, stream>>>(Whh, ws + OFF_WHH, GG);
  k_wt4<<<160, 256, 0, stream>>>(Wout, ws + OFF_WOUT, VV);
  k_pgemm<<<640, 256, 0, stream>>>(E, Wih, ws + OFF_P);
  k_init<<<4, 256, 0, stream>>>(ws, bl);
  k_decode<<<NBLK, 256, 0, stream>>>(ws, tn, bl, bj, bo, out);
  k_final<<<1, 64, 0, stream>>>(ws, out);
}

// Round 5
// 28314.435 us; speedup vs baseline: 4.6856x; 1.2731x over previous
//
#include <hip/hip_runtime.h>
#include <stdint.h>

// Transducer greedy decode, persistent 3-stage pipeline.
// R4 post-mortem: 2 issues attacked here:
//  (a) CU sharing: VGPR128/LDS43.5KB allowed up to 3 blocks/CU -> laggard-paced
//      pipeline + 36<->66us replay variance. Fix: ~124KB LDS/block forces
//      exclusive CU residency.
//  (b) poll-traffic: ~10k spinning pollers hammered LLC. Fix: per-handoff
//      aggregator block publishes a single epoch line; consumers poll it with
//      ONE thread.
// Also: A computes Wtn.tn_t BEFORE waiting for h (immutable input, hides HBM
// latency, halves A's critical-path compute); C reads h coherently once into
// an LDS stash (stride 648, conflict-free) reused by both Whh passes.
// Stages (224 blk x 256 thr, 1 blk/CU): A(80): z=tanh(Wtn.x+Wpn.h+bj)
// L(64): logits -> per-block argmax/sumexp slots (zero-RMW, R4-validated)
// C(80): Whh.h + slot-reduce + decode + LSTM elementwise.
// Chain: C(t-1) -> A(t) -> L(t) -> C-tail(t).

typedef unsigned long long u64;
typedef uint32_t u32;

#define TT 1000
#define DD 640
#define GG 2560
#define VV 1024

#define NA 80
#define NL 64
#define NC 80
#define NBLK (NA + NL + NC) // 224

// ws layout (float offsets)
static constexpr size_t OFF_WTN  = 0;                      // 640x640  WT4
static constexpr size_t OFF_WPN  = OFF_WTN  + 409600;
static constexpr size_t OFF_WHH  = OFF_WPN  + 409600;      // 2560x640
static constexpr size_t OFF_WOUT = OFF_WHH  + 1638400;     // 1024x640
static constexpr size_t OFF_P    = OFF_WOUT + 655360;      // 1024x2560
static constexpr size_t OFF_XH   = OFF_P    + 2621440;     // h [2 par][32][640]
static constexpr size_t OFF_XZ   = OFF_XH   + 40960;       // z [32][640]
static constexpr size_t OFF_SC   = OFF_XZ   + 20480;       // score[32]
static constexpr size_t OFF_LKEY = OFF_SC   + 32;          // u64 [32][64] slots
static constexpr size_t OFF_LSE  = OFF_LKEY + 4096;        // f32 [32][64] slots
static constexpr size_t OFF_FA   = OFF_LSE  + 2048;        // 80 flags, stride 32
static constexpr size_t OFF_FL   = OFF_FA   + 2560;        // 64 flags
static constexpr size_t OFF_FC   = OFF_FL   + 2048;        // 80 flags
static constexpr size_t OFF_EP   = OFF_FC   + 2560;        // 3 epochs, stride 32
static constexpr size_t OFF_END  = OFF_EP   + 96;          // ~23.2 MB

__device__ __forceinline__ float sigf(float x) { return 1.0f / (1.0f + expf(-x)); }

__device__ __forceinline__ u32 ordf(float f) {
  u32 u = __float_as_uint(f);
  return (u & 0x80000000u) ? ~u : (u | 0x80000000u);
}

// ---- coherent (LLC) accesses: bypass L1/L2, no fences (R3/R4-validated) ----
__device__ __forceinline__ void cstore2(float* p, float a, float b) {
  u64 v = ((u64)__float_as_uint(b) << 32) | (u64)__float_as_uint(a);
  __hip_atomic_store((u64*)p, v, __ATOMIC_RELAXED, __HIP_MEMORY_SCOPE_AGENT);
}
__device__ __forceinline__ float2 cload2(const float* p) {
  u64 v = __hip_atomic_load((const u64*)p, __ATOMIC_RELAXED, __HIP_MEMORY_SCOPE_AGENT);
  return make_float2(__uint_as_float((u32)v), __uint_as_float((u32)(v >> 32)));
}
__device__ __forceinline__ u64 cloadu64(const u64* p) {
  return __hip_atomic_load(p, __ATOMIC_RELAXED, __HIP_MEMORY_SCOPE_AGENT);
}
__device__ __forceinline__ void cstoreu64(u64* p, u64 v) {
  __hip_atomic_store(p, v, __ATOMIC_RELAXED, __HIP_MEMORY_SCOPE_AGENT);
}
__device__ __forceinline__ float cloadf(const float* p) {
  return __hip_atomic_load(p, __ATOMIC_RELAXED, __HIP_MEMORY_SCOPE_AGENT);
}
__device__ __forceinline__ void cstoref(float* p, float v) {
  __hip_atomic_store(p, v, __ATOMIC_RELAXED, __HIP_MEMORY_SCOPE_AGENT);
}

// aggregator: poll n per-block flags (1 thread per flag), then sync.
__device__ __forceinline__ void poll_flags(const int* F, int n, int target) {
  if ((int)threadIdx.x < n) {
    while (__hip_atomic_load(F + threadIdx.x * 32, __ATOMIC_RELAXED,
                             __HIP_MEMORY_SCOPE_AGENT) < target)
      __builtin_amdgcn_s_sleep(1);
  }
  __syncthreads();
}
// consumer: poll a single epoch line with one thread.
__device__ __forceinline__ void poll1(const int* ep, int target) {
  if (threadIdx.x == 0) {
    while (__hip_atomic_load(ep, __ATOMIC_RELAXED, __HIP_MEMORY_SCOPE_AGENT) < target)
      __builtin_amdgcn_s_sleep(1);
  }
  __syncthreads();
}
// release: barrier drains all waves' vmcnt (stores at LLC), then plain flag store.
__device__ __forceinline__ void set_flag(int* F, int idx, int val) {
  __syncthreads();
  if (threadIdx.x == 0)
    __hip_atomic_store(F + idx * 32, val, __ATOMIC_RELAXED, __HIP_MEMORY_SCOPE_AGENT);
}

__device__ __forceinline__ void fma4(float& a, const float4 w, const float4 x) {
  a = fmaf(w.x, x.x, fmaf(w.y, x.y, fmaf(w.z, x.z, fmaf(w.w, x.w, a))));
}
__device__ __forceinline__ void fma22(float& a, const float4 w, const float2 xa,
                                      const float2 xb) {
  a = fmaf(w.x, xa.x, fmaf(w.y, xa.y, fmaf(w.z, xb.x, fmaf(w.w, xb.y, a))));
}

// ---- setup kernels ----

// W[j][d] (row-major, K=640) -> WT4: float4 at (d/4)*J + j holds W[j][4q..4q+3]
__global__ __launch_bounds__(256) void k_wt4(const float* __restrict__ W,
                                             float* __restrict__ WT4, int J) {
  __shared__ float tile[64][65];
  int nj = J >> 6;
  int tj = blockIdx.x % nj, tk = blockIdx.x / nj;
  int jb = tj << 6, kb = tk << 6;
  for (int i = threadIdx.x; i < 4096; i += 256) {
    int d = i & 63, j = i >> 6;
    tile[j][d] = W[(size_t)(jb + j) * DD + (kb + d)];
  }
  __syncthreads();
  for (int i = threadIdx.x; i < 1024; i += 256) {
    int j = i & 63, q = i >> 6;
    float4 v = make_float4(tile[j][q * 4], tile[j][q * 4 + 1], tile[j][q * 4 + 2],
                           tile[j][q * 4 + 3]);
    ((float4*)WT4)[(size_t)((kb >> 2) + q) * J + (jb + j)] = v;
  }
}

// P[v][g] = sum_d E[v][d] * Wih[g][d]
__global__ __launch_bounds__(256) void k_pgemm(const float* __restrict__ E,
                                               const float* __restrict__ Wih,
                                               float* __restrict__ P) {
  __shared__ float As[16][65], Bs[16][65];
  int vt = blockIdx.x & 15, gt = blockIdx.x >> 4;
  int vb = vt << 6, gb = gt << 6;
  int tv = threadIdx.x & 15, tg = threadIdx.x >> 4;
  float acc[4][4] = {};
  for (int kb = 0; kb < DD; kb += 16) {
    for (int i = threadIdx.x; i < 1024; i += 256) {
      int k = i & 15, x = i >> 4;
      As[k][x] = E[(size_t)(vb + x) * DD + kb + k];
      Bs[k][x] = Wih[(size_t)(gb + x) * DD + kb + k];
    }
    __syncthreads();
#pragma unroll
    for (int k = 0; k < 16; ++k) {
      float av[4], bv[4];
#pragma unroll
      for (int i = 0; i < 4; ++i) av[i] = As[k][tv * 4 + i];
#pragma unroll
      for (int j = 0; j < 4; ++j) bv[j] = Bs[k][tg * 4 + j];
#pragma unroll
      for (int i = 0; i < 4; ++i)
#pragma unroll
        for (int j = 0; j < 4; ++j) acc[i][j] = fmaf(av[i], bv[j], acc[i][j]);
    }
    __syncthreads();
  }
#pragma unroll
  for (int i = 0; i < 4; ++i)
#pragma unroll
    for (int j = 0; j < 4; ++j)
      P[(size_t)(vb + tv * 4 + i) * GG + gb + tg * 4 + j] = acc[i][j];
}

// initial LSTM step: x0=E[0], h0=c0=0 -> h1 identical for all b; XH parity 0.
__global__ __launch_bounds__(256) void k_init(float* __restrict__ ws,
                                              const float* __restrict__ bl) {
  const float* P = ws + OFF_P;
  float* XH0 = ws + OFF_XH;
  int tid = blockIdx.x * 256 + threadIdx.x;
  if (tid < DD) {
    int j = tid;
    float gi = P[j] + bl[j];
    float gg = P[1280 + j] + bl[1280 + j];
    float go = P[1920 + j] + bl[1920 + j];
    float c1 = sigf(gi) * tanhf(gg);
    float h1 = sigf(go) * tanhf(c1);
    for (int b = 0; b < 32; ++b) XH0[b * DD + j] = h1;
  }
  if (blockIdx.x == 3) {
    int* FA = (int*)(ws + OFF_FA);
    int* FL = (int*)(ws + OFF_FL);
    int* FC = (int*)(ws + OFF_FC);
    int* EP = (int*)(ws + OFF_EP);
    for (int i = threadIdx.x; i < 224; i += 256) {
      int* p = (i < 80) ? (FA + i * 32)
                        : (i < 144) ? (FL + (i - 80) * 32) : (FC + (i - 144) * 32);
      *p = 0;
    }
    if (threadIdx.x < 3) EP[threadIdx.x * 32] = 0;
  }
}

// ---- persistent decode ----
__global__ __launch_bounds__(256, 1) void k_decode(float* __restrict__ ws,
                                                   const float* __restrict__ tn,
                                                   const float* __restrict__ bl,
                                                   const float* __restrict__ bj,
                                                   const float* __restrict__ bo,
                                                   float* __restrict__ out) {
  const float* WTN = ws + OFF_WTN;
  const float* WPN = ws + OFF_WPN;
  const float* WHH = ws + OFF_WHH;
  const float* WOUT = ws + OFF_WOUT;
  const float* P = ws + OFF_P;
  float* XH = ws + OFF_XH;
  float* XZ = ws + OFF_XZ;
  float* SCg = ws + OFF_SC;
  u64* LKEY = (u64*)(ws + OFF_LKEY);
  float* LSE = ws + OFF_LSE;
  int* FA = (int*)(ws + OFF_FA);
  int* FL = (int*)(ws + OFF_FL);
  int* FC = (int*)(ws + OFF_FC);
  int* EFC = (int*)(ws + OFF_EP) + 0;   // "h(t) ready" epoch (A0 aggregates FC)
  int* EFA = (int*)(ws + OFF_EP) + 32;  // "z(t) ready"  (L0 aggregates FA)
  int* EFL = (int*)(ws + OFF_EP) + 64;  // "logits(t) ready" (C0 aggregates FL)

  // ~124 KB static LDS: functional + forces 1 block/CU (exclusive residency).
  __shared__ float xbuf[32 * 648];     // 82.9 KB: C's h stash (stride 648:
                                       // 16B-aligned per row, conflict-free)
  __shared__ float red[16 * 16 * 33];  // 33.8 KB partial sums
  __shared__ float aux[32 * 33];       // A: z rows; L: logit tile; C: gates
  __shared__ u64 kred[32 * 9];
  __shared__ float sered[32 * 9];
  __shared__ float c_lds[8 * 33], h_lds[8 * 33];
  __shared__ float sc_lds[32];
  __shared__ int tok_lds[32], nb_lds[32], lt_lds[32];

  const int bid = blockIdx.x, tid = threadIdx.x;
  const int dq = tid >> 4, bp = tid & 15; // 16 d-groups x 16 b-pairs (unique x)
  const int d0 = dq * 40, b0 = bp * 2;

  if (bid < NA) {
    // ---- stage A: XZ = tanh(W_tn.tn_t + W_pn.h + b_joint), 8 j rows ----
    const int j0 = bid * 8;
    for (int t = 0; t < TT; ++t) {
      const int par = t & 1;
      // (1) Wtn part BEFORE waiting for h: immutable input, hides tn latency.
      float acc[8][2] = {};
      const float* t0p = tn + ((size_t)b0 * TT + t) * DD + d0;
      const float* t1p = t0p + (size_t)TT * DD;
#pragma unroll 5
      for (int q = 0; q < 10; ++q) {
        float4 x0 = *(const float4*)(t0p + q * 4);
        float4 x1 = *(const float4*)(t1p + q * 4);
        const float4* wt = (const float4*)WTN + (size_t)((d0 + q * 4) >> 2) * DD + j0;
#pragma unroll
        for (int r = 0; r < 8; ++r) {
          fma4(acc[r][0], wt[r], x0);
          fma4(acc[r][1], wt[r], x1);
        }
      }
      // (2) wait for h(t)
      if (bid == 0) {
        poll_flags(FC, NC, t);
        if (tid == 0)
          __hip_atomic_store(EFC, t, __ATOMIC_RELAXED, __HIP_MEMORY_SCOPE_AGENT);
      } else {
        poll1(EFC, t);
      }
      // (3) Wpn part
      const float* h0p = XH + (size_t)par * 20480 + (size_t)b0 * DD + d0;
      const float* h1p = h0p + DD;
#pragma unroll 5
      for (int q = 0; q < 10; ++q) {
        float2 a0 = cload2(h0p + q * 4), a1 = cload2(h0p + q * 4 + 2);
        float2 b1 = cload2(h1p + q * 4), b2 = cload2(h1p + q * 4 + 2);
        const float4* wp = (const float4*)WPN + (size_t)((d0 + q * 4) >> 2) * DD + j0;
#pragma unroll
        for (int r = 0; r < 8; ++r) {
          fma22(acc[r][0], wp[r], a0, a1);
          fma22(acc[r][1], wp[r], b1, b2);
        }
      }
#pragma unroll
      for (int r = 0; r < 8; ++r) {
        red[(dq * 8 + r) * 33 + b0] = acc[r][0];
        red[(dq * 8 + r) * 33 + b0 + 1] = acc[r][1];
      }
      __syncthreads();
      {
        int r = tid >> 5, b = tid & 31;
        float s = 0.f;
#pragma unroll
        for (int k = 0; k < 16; ++k) s += red[(k * 8 + r) * 33 + b];
        aux[r * 33 + b] = tanhf(s + bj[j0 + r]);
      }
      __syncthreads();
      if (tid < 128) {
        int jp = tid >> 5, b = tid & 31;
        cstore2(XZ + (size_t)b * DD + j0 + jp * 2, aux[(jp * 2) * 33 + b],
                aux[(jp * 2 + 1) * 33 + b]);
      }
      set_flag(FA, bid, t + 1);
    }
  } else if (bid < NA + NL) {
    // ---- stage L: 16-v logit tile -> per-block slots (zero-RMW) ----
    const int lb = bid - NA, v0 = lb * 16;
    for (int t = 0; t < TT; ++t) {
      if (lb == 0) {
        poll_flags(FA, NA, t + 1);
        if (tid == 0)
          __hip_atomic_store(EFA, t + 1, __ATOMIC_RELAXED, __HIP_MEMORY_SCOPE_AGENT);
      } else {
        poll1(EFA, t + 1);
      }
      const float* z0p = XZ + (size_t)b0 * DD + d0;
      const float* z1p = z0p + DD;
      float acc[16][2] = {};
#pragma unroll 5
      for (int q = 0; q < 10; ++q) {
        float2 z0a = cload2(z0p + q * 4), z0b = cload2(z0p + q * 4 + 2);
        float2 z1a = cload2(z1p + q * 4), z1b = cload2(z1p + q * 4 + 2);
        const float4* wo = (const float4*)WOUT + (size_t)((d0 + q * 4) >> 2) * VV + v0;
#pragma unroll
        for (int r = 0; r < 16; ++r) {
          float4 w = wo[r];
          fma22(acc[r][0], w, z0a, z0b);
          fma22(acc[r][1], w, z1a, z1b);
        }
      }
#pragma unroll
      for (int r = 0; r < 16; ++r) {
        red[(dq * 16 + r) * 33 + b0] = acc[r][0];
        red[(dq * 16 + r) * 33 + b0 + 1] = acc[r][1];
      }
      __syncthreads();
#pragma unroll
      for (int o = tid; o < 512; o += 256) {
        int r = o >> 5, b = o & 31;
        float s = bo[v0 + r];
#pragma unroll
        for (int k = 0; k < 16; ++k) s += red[(k * 16 + r) * 33 + b];
        aux[r * 33 + b] = s;
      }
      __syncthreads();
      if (tid < 32) {
        int b = tid;
        float m = -1e30f, se = 0.f;
        int vbest = 0;
#pragma unroll
        for (int r = 0; r < 16; ++r) {
          float x = aux[r * 33 + b];
          se += expf(x);
          if (x > m) { m = x; vbest = r; } // strict > => first occurrence
        }
        u64 key = ((u64)ordf(m) << 32) | (u64)(0xFFFFFFFFu - (u32)(v0 + vbest));
        cstoreu64(&LKEY[(size_t)b * 64 + lb], key);
        cstoref(&LSE[(size_t)b * 64 + lb], se);
      }
      set_flag(FL, lb, t + 1);
    }
  } else {
    // ---- stage C: gates = W_hh.h (LDS-stashed h, 2 passes of 16 rows),
    //      slot-reduce argmax, decode, LSTM elementwise ----
    const int cb = bid - (NA + NL), j0 = cb * 8;
    {
      int jj = tid >> 5, b = tid & 31, j = j0 + jj;
      float gi = P[j] + bl[j];
      float gg = P[1280 + j] + bl[1280 + j];
      float go = P[1920 + j] + bl[1920 + j];
      float c1 = sigf(gi) * tanhf(gg);
      c_lds[jj * 33 + b] = c1;
      h_lds[jj * 33 + b] = sigf(go) * tanhf(c1);
    }
    if (tid < 32) { lt_lds[tid] = 0; sc_lds[tid] = 0.f; }
    __syncthreads();
    for (int t = 0; t < TT; ++t) {
      const int par = t & 1;
      poll1(EFC, t); // h(t) ready (aggregated by A0)
      // stash h into LDS once (coherent reads, unique coverage)
      {
        const float* h0p = XH + (size_t)par * 20480 + (size_t)b0 * DD + d0;
        const float* h1p = h0p + DD;
#pragma unroll 5
        for (int q = 0; q < 10; ++q) {
          float2 a0 = cload2(h0p + q * 4), a1 = cload2(h0p + q * 4 + 2);
          float2 b1 = cload2(h1p + q * 4), b2 = cload2(h1p + q * 4 + 2);
          *(float4*)&xbuf[b0 * 648 + d0 + q * 4] = make_float4(a0.x, a0.y, a1.x, a1.y);
          *(float4*)&xbuf[(b0 + 1) * 648 + d0 + q * 4] = make_float4(b1.x, b1.y, b2.x, b2.y);
        }
      }
      __syncthreads();
#pragma unroll
      for (int p = 0; p < 2; ++p) {
        float acc[16][2] = {};
#pragma unroll 5
        for (int q = 0; q < 10; ++q) {
          const int d = d0 + q * 4;
          float4 h0 = *(const float4*)&xbuf[b0 * 648 + d];
          float4 h1 = *(const float4*)&xbuf[(b0 + 1) * 648 + d];
          const float4* wa =
              (const float4*)WHH + (size_t)(d >> 2) * GG + (2 * p) * DD + j0;
          const float4* wb = wa + DD;
#pragma unroll
          for (int jj = 0; jj < 8; ++jj) {
            fma4(acc[jj][0], wa[jj], h0);
            fma4(acc[jj][1], wa[jj], h1);
            fma4(acc[8 + jj][0], wb[jj], h0);
            fma4(acc[8 + jj][1], wb[jj], h1);
          }
        }
#pragma unroll
        for (int r = 0; r < 16; ++r) {
          red[(dq * 16 + r) * 33 + b0] = acc[r][0];
          red[(dq * 16 + r) * 33 + b0 + 1] = acc[r][1];
        }
        __syncthreads();
#pragma unroll
        for (int o = tid; o < 512; o += 256) {
          int r16 = o >> 5, b = o & 31;
          float s = 0.f;
#pragma unroll
          for (int k = 0; k < 16; ++k) s += red[(k * 16 + r16) * 33 + b];
          int g = 2 * p + (r16 >> 3), jj = r16 & 7;
          aux[(g * 8 + jj) * 33 + b] = s; // gates
        }
        __syncthreads();
      }
      if (cb == 0) {
        poll_flags(FL, NL, t + 1);
        if (tid == 0)
          __hip_atomic_store(EFL, t + 1, __ATOMIC_RELAXED, __HIP_MEMORY_SCOPE_AGENT);
      } else {
        poll1(EFL, t + 1);
      }
      // tree-reduce per-block argmax/sumexp slots (coalesced, deterministic)
      {
        int b = tid >> 3, ch = tid & 7;
        const u64* kp = LKEY + (size_t)b * 64 + ch * 8;
        u64 km = 0;
#pragma unroll
        for (int i = 0; i < 8; ++i) {
          u64 x = cloadu64(kp + i);
          km = x > km ? x : km;
        }
        kred[b * 9 + ch] = km;
        if (cb == 0) {
          const float* sp = LSE + (size_t)b * 64 + ch * 8;
          float ss = 0.f;
#pragma unroll
          for (int i = 0; i < 8; ++i) ss += cloadf(sp + i);
          sered[b * 9 + ch] = ss;
        }
      }
      __syncthreads();
      if (tid < 32) {
        int b = tid;
        u64 km = 0;
#pragma unroll
        for (int ch = 0; ch < 8; ++ch) {
          u64 x = kred[b * 9 + ch];
          km = x > km ? x : km;
        }
        u32 ou = (u32)(km >> 32);
        u32 fb = (ou & 0x80000000u) ? (ou & 0x7FFFFFFFu) : ~ou;
        float m = __uint_as_float(fb);
        int v = (int)(0xFFFFFFFFu - (u32)(km & 0xFFFFFFFFull));
        int nb = (v != 0) ? 1 : 0;
        int tok = nb ? v : lt_lds[b];
        lt_lds[b] = tok;
        tok_lds[b] = tok;
        nb_lds[b] = nb;
        if (cb == 0) {
          float S = 0.f;
#pragma unroll
          for (int ch = 0; ch < 8; ++ch) S += sered[b * 9 + ch];
          float lp = m - logf(S); // logits bounded: no max-shift needed
          if (nb) sc_lds[b] += lp;
          out[(size_t)b * TT + t] = nb ? (float)v : 0.0f;
          if (t == TT - 1) SCg[b] = sc_lds[b];
        }
      }
      __syncthreads();
      {
        int jj = tid >> 5, b = tid & 31, j = j0 + jj;
        if (nb_lds[b]) {
          const float* Pr = P + (size_t)tok_lds[b] * GG;
          float gi = aux[(0 + jj) * 33 + b] + Pr[j] + bl[j];
          float gf = aux[(8 + jj) * 33 + b] + Pr[640 + j] + bl[640 + j];
          float gg = aux[(16 + jj) * 33 + b] + Pr[1280 + j] + bl[1280 + j];
          float go = aux[(24 + jj) * 33 + b] + Pr[1920 + j] + bl[1920 + j];
          float c = c_lds[jj * 33 + b];
          float cn = sigf(gf) * c + sigf(gi) * tanhf(gg);
          float hn = sigf(go) * tanhf(cn);
          c_lds[jj * 33 + b] = cn;
          h_lds[jj * 33 + b] = hn;
        }
      }
      __syncthreads();
      if (tid < 128) {
        int jp = tid >> 5, b = tid & 31;
        cstore2(XH + (size_t)(1 - par) * 20480 + (size_t)b * DD + j0 + jp * 2,
                h_lds[(jp * 2) * 33 + b], h_lds[(jp * 2 + 1) * 33 + b]);
      }
      set_flag(FC, cb, t + 1);
    }
  }
}

__global__ __launch_bounds__(64) void k_final(const float* __restrict__ ws,
                                              float* __restrict__ out) {
  __shared__ float sh[32];
  int t = threadIdx.x;
  if (t < 32) {
    float s = ws[OFF_SC + t];
    out[32000 + t] = s;
    sh[t] = expf(s);
  }
  __syncthreads();
  if (t == 0) {
    float a = 0.f;
    for (int i = 0; i < 32; ++i) a += sh[i];
    out[32032] = a / 32.0f;
  }
}

extern "C" void kernel_launch(void* const* d_in, const int* in_sizes, int n_in,
                              void* d_out, int out_size, void* d_ws, size_t ws_size,
                              hipStream_t stream) {
  const float* tn = (const float*)d_in[0];
  const float* E = (const float*)d_in[1];
  const float* Wih = (const float*)d_in[2];
  const float* Whh = (const float*)d_in[3];
  const float* bl = (const float*)d_in[4];
  const float* Wtn = (const float*)d_in[5];
  const float* Wpn = (const float*)d_in[6];
  const float* bj = (const float*)d_in[7];
  const float* Wout = (const float*)d_in[8];
  const float* bo = (const float*)d_in[9];
  float* ws = (float*)d_ws;
  float* out = (float*)d_out;

  k_wt4<<<100, 256, 0, stream>>>(Wtn, ws + OFF_WTN, DD);
  k_wt4<<<100, 256, 0, stream>>>(Wpn, ws + OFF_WPN, DD);
  k_wt4<<<400, 256, 0, stream>>>(Whh, ws + OFF_WHH, GG);
  k_wt4<<<160, 256, 0, stream>>>(Wout, ws + OFF_WOUT, VV);
  k_pgemm<<<640, 256, 0, stream>>>(E, Wih, ws + OFF_P);
  k_init<<<4, 256, 0, stream>>>(ws, bl);
  k_decode<<<NBLK, 256, 0, stream>>>(ws, tn, bl, bj, bo, out);
  k_final<<<1, 64, 0, stream>>>(ws, out);
}